// Round 1
// baseline (31316.779 us; speedup 1.0000x reference)
//
#include <hip/hip_runtime.h>

#define TPB 256
#define NWG 64

// ---------------------------------------------------------------------------
// Generic tiled fp32 GEMM: Z[M x N] = X[M x K] @ Y[K x N], row-major.
// 64x64 tile, 256 threads, 4x4 micro-tile per thread, k-tile 16.
// ---------------------------------------------------------------------------
__global__ __launch_bounds__(256) void gemm_kernel(const float* __restrict__ X,
    const float* __restrict__ Y, float* __restrict__ Z, int M, int N, int Kd) {
  __shared__ float Xs[16][65];
  __shared__ float Ys[16][65];
  const int tx = threadIdx.x & 15;
  const int ty = threadIdx.x >> 4;
  const int mbase = blockIdx.y * 64;
  const int nbase = blockIdx.x * 64;
  float acc[4][4] = {};
  for (int k0 = 0; k0 < Kd; k0 += 16) {
#pragma unroll
    for (int r = 0; r < 4; ++r) {
      int idx = threadIdx.x + 256 * r;
      int mm = idx >> 4, kk = idx & 15;
      int gm = mbase + mm, gk = k0 + kk;
      Xs[kk][mm] = (gm < M && gk < Kd) ? X[(size_t)gm * Kd + gk] : 0.f;
      int nn = idx & 63, k2 = idx >> 6;
      int gn = nbase + nn, gk2 = k0 + k2;
      Ys[k2][nn] = (gk2 < Kd && gn < N) ? Y[(size_t)gk2 * N + gn] : 0.f;
    }
    __syncthreads();
#pragma unroll
    for (int kk = 0; kk < 16; ++kk) {
      float xv[4], yv[4];
#pragma unroll
      for (int a = 0; a < 4; ++a) xv[a] = Xs[kk][ty * 4 + a];
#pragma unroll
      for (int b = 0; b < 4; ++b) yv[b] = Ys[kk][tx * 4 + b];
#pragma unroll
      for (int a = 0; a < 4; ++a)
#pragma unroll
        for (int b = 0; b < 4; ++b) acc[a][b] += xv[a] * yv[b];
    }
    __syncthreads();
  }
#pragma unroll
  for (int a = 0; a < 4; ++a) {
    int gm = mbase + ty * 4 + a;
    if (gm < M) {
#pragma unroll
      for (int b = 0; b < 4; ++b) {
        int gn = nbase + tx * 4 + b;
        if (gn < N) Z[(size_t)gm * N + gn] = acc[a][b];
      }
    }
  }
}

// ---------------------------------------------------------------------------
// M2[c][i][q] = sum_j M_tensor[c][i][j][q] * s_m[j]
// ---------------------------------------------------------------------------
__global__ __launch_bounds__(256) void m2_kernel(const float* __restrict__ MT,
    const float* __restrict__ sm, float* __restrict__ M2g) {
  int idx = blockIdx.x * 256 + threadIdx.x;  // c*8192 + i*256 + q
  if (idx >= 128 * 32 * 256) return;
  int q = idx & 255;
  int ci = idx >> 8;  // c*32 + i
  const float* base = MT + (size_t)ci * 32 * 256 + q;
  float acc = 0.f;
#pragma unroll
  for (int j = 0; j < 32; ++j) acc += base[j * 256] * sm[j];
  M2g[idx] = acc;
}

// ---------------------------------------------------------------------------
// W0[c][q] = sum_i M2[c][i][q]*Phi[i][0];  W1 same with Phi[i][1]
// ---------------------------------------------------------------------------
__global__ __launch_bounds__(256) void w01_kernel(const float* __restrict__ M2g,
    const float* __restrict__ Phi, float* __restrict__ W0, float* __restrict__ W1m) {
  int idx = blockIdx.x * 256 + threadIdx.x;  // c*256 + q
  if (idx >= 128 * 256) return;
  int q = idx & 255, c = idx >> 8;
  float a0 = 0.f, a1 = 0.f;
#pragma unroll
  for (int i = 0; i < 32; ++i) {
    float m = M2g[((size_t)(c * 32 + i)) * 256 + q];
    a0 += m * Phi[i * 64];
    a1 += m * Phi[i * 64 + 1];
  }
  W0[idx] = a0;
  W1m[idx] = a1;
}

// ---------------------------------------------------------------------------
// init: x_hist[0]=x0, d_0=x0, zero ytail slots, zero barrier counter
// ---------------------------------------------------------------------------
__global__ void init_kernel(const float* __restrict__ x0, float* __restrict__ xh,
    float* __restrict__ dbuf, float* __restrict__ ytail, unsigned* __restrict__ bar) {
  int tid = blockIdx.x * 256 + threadIdx.x;
  if (tid < 512) {
    xh[tid] = x0[tid];
    dbuf[tid] = x0[tid];
    dbuf[512 + tid] = 0.f;
  }
  if (tid < 16384) ytail[tid] = 0.f;
  if (tid == 0) *bar = 0u;
}

// ---------------------------------------------------------------------------
// grid barrier: monotonic counter, agent-scope atomics
// ---------------------------------------------------------------------------
__device__ __forceinline__ void grid_barrier(unsigned* bar, unsigned target) {
  __syncthreads();
  if (threadIdx.x == 0) {
    __threadfence();
    __hip_atomic_fetch_add(bar, 1u, __ATOMIC_ACQ_REL, __HIP_MEMORY_SCOPE_AGENT);
    while (__hip_atomic_load(bar, __ATOMIC_ACQUIRE, __HIP_MEMORY_SCOPE_AGENT) < target) {
    }
    __threadfence();
  }
  __syncthreads();
}

// ---------------------------------------------------------------------------
// Persistent main loop: one grid barrier per timestep.
// Per phase t (all inputs from phase <= t-1):
//   x_t       = A x_{t-1} + B u_{t-1}                      (t>=1; x_0 preset)
//   y_obs_t   = CA x_{t-1} + CB u_{t-1}   (t=0: C x0)
//   y_nat_t   = C d_t
//   d_{t+1}   = A d_t + A33B u_{t-33}
//   ytail2_{t+1}[i,q] = sum_{j=2..63} Phi[i,j] y_nat_{t+1-j}[q]
//   u_t[c]    = -KCA x_{t-1} - KCB u_{t-1} + W0C d_t + W1 y_nat_{t-1}
//               + sum_{i,q} M2[c,i,q] ytail2_t[i,q]        (t=0: -KC x0 + W0C x0)
// M2 c-slice (2 rows, 64KB) is pinned in LDS per workgroup.
// ---------------------------------------------------------------------------
__global__ __launch_bounds__(TPB, 1) void main_kernel(
    const float* __restrict__ A, const float* __restrict__ B, const float* __restrict__ C,
    const float* __restrict__ x0, const float* __restrict__ Phi,
    const float* __restrict__ M2g, const float* __restrict__ W0C,
    const float* __restrict__ W1m, const float* __restrict__ KC,
    const float* __restrict__ KCA, const float* __restrict__ KCB,
    const float* __restrict__ CA, const float* __restrict__ CB,
    const float* __restrict__ A33B,
    float* __restrict__ xh, float* __restrict__ uh, float* __restrict__ ynh,
    float* __restrict__ yoh, float* __restrict__ dbuf, float* __restrict__ ytail,
    unsigned* __restrict__ bar) {
  __shared__ float m2s[16384];  // 2 x (32*256)
  __shared__ float red[TPB];
  const int bid = blockIdx.x;
  const int tid = threadIdx.x;
  const int c0 = bid * 2;
  for (int i = tid; i < 16384; i += TPB) m2s[i] = M2g[(size_t)c0 * 8192 + i];
  __syncthreads();

  const int wave = (bid << 2) | (tid >> 6);
  const int lane = tid & 63;
  const int grp = (wave << 3) | (lane >> 3);  // 0..2047
  const int ls = lane & 7;

#pragma unroll 1
  for (int t = 0; t < 1024; ++t) {
    const float* xprev = (t > 0) ? (xh + (size_t)(t - 1) * 512) : x0;
    const float* uprev = uh + (size_t)(t > 0 ? t - 1 : 0) * 128;
    const float* dcur = dbuf + (t & 1) * 512;
    float* dnext = dbuf + ((t + 1) & 1) * 512;
    const float* ytcur = ytail + (t & 1) * 8192;
    float* ytnext = ytail + ((t + 1) & 1) * 8192;

    // ---- (a)-(d): 8-lane-group matvec tasks, groups 0..1535 (WGs 0..47) ----
    if (grp < 1536) {
      float acc = 0.f;
      float* dstp = nullptr;
      if (grp < 512) {  // x_t[d]
        if (t > 0) {
          const int d = grp;
          const float* Ar = A + (size_t)d * 512;
          for (int k = ls; k < 512; k += 8) acc += Ar[k] * xprev[k];
          const float* Br = B + (size_t)d * 128;
          for (int k = ls; k < 128; k += 8) acc += Br[k] * uprev[k];
          dstp = xh + (size_t)t * 512 + d;
        }
      } else if (grp < 768) {  // y_obs_t[p]
        const int p = grp - 512;
        if (t == 0) {
          const float* Cr = C + (size_t)p * 512;
          for (int k = ls; k < 512; k += 8) acc += Cr[k] * x0[k];
        } else {
          const float* CAr = CA + (size_t)p * 512;
          for (int k = ls; k < 512; k += 8) acc += CAr[k] * xprev[k];
          const float* CBr = CB + (size_t)p * 128;
          for (int k = ls; k < 128; k += 8) acc += CBr[k] * uprev[k];
        }
        dstp = yoh + (size_t)t * 256 + p;
      } else if (grp < 1024) {  // y_nat_t[p] = C d_t
        const int p = grp - 768;
        const float* Cr = C + (size_t)p * 512;
        for (int k = ls; k < 512; k += 8) acc += Cr[k] * dcur[k];
        dstp = ynh + (size_t)t * 256 + p;
      } else {  // d_{t+1}[d]
        const int d = grp - 1024;
        const float* Ar = A + (size_t)d * 512;
        for (int k = ls; k < 512; k += 8) acc += Ar[k] * dcur[k];
        if (t >= 33) {
          const float* u33 = uh + (size_t)(t - 33) * 128;
          const float* Pr = A33B + (size_t)d * 128;
          for (int k = ls; k < 128; k += 8) acc += Pr[k] * u33[k];
        }
        dstp = dnext + d;
      }
      acc += __shfl_down(acc, 4);
      acc += __shfl_down(acc, 2);
      acc += __shfl_down(acc, 1);
      if (ls == 0 && dstp) *dstp = acc;
    }

    // ---- (e): ytail2_{t+1}[i][q], WGs 48..63, two outputs/thread ----
    if (bid >= 48) {
      int base = ((bid - 48) << 8) | tid;  // 0..4095
#pragma unroll
      for (int rr = 0; rr < 2; ++rr) {
        int idx = base + rr * 4096;
        int i = idx >> 8, q = idx & 255;
        float acc = 0.f;
        int jmax = (t + 1 < 64) ? (t + 1) : 63;
        for (int j = 2; j <= jmax; ++j)
          acc += Phi[(i << 6) | j] * ynh[(size_t)(t + 1 - j) * 256 + q];
        ytnext[idx] = acc;
      }
    }

    // ---- (f): u_t[c0 + (tid>>7)] ----
    {
      const int half = tid >> 7;
      const int k = tid & 127;
      const int c = c0 + half;
      float acc = 0.f;
      const float* m2c = m2s + half * 8192;
#pragma unroll 8
      for (int n = 0; n < 64; ++n) {
        int iq = k + (n << 7);
        acc += m2c[iq] * ytcur[iq];
      }
      const float* w0cr = W0C + (size_t)c * 512;
      for (int kk = k; kk < 512; kk += 128) acc += w0cr[kk] * dcur[kk];
      if (t == 0) {
        const float* kcr = KC + (size_t)c * 512;
        for (int kk = k; kk < 512; kk += 128) acc -= kcr[kk] * x0[kk];
      } else {
        const float* kcar = KCA + (size_t)c * 512;
        for (int kk = k; kk < 512; kk += 128) acc -= kcar[kk] * xprev[kk];
        acc -= KCB[(size_t)c * 128 + k] * uprev[k];
        const float* ynp = ynh + (size_t)(t - 1) * 256;
        const float* w1r = W1m + (size_t)c * 256;
        acc += w1r[k] * ynp[k] + w1r[k + 128] * ynp[k + 128];
      }
      red[tid] = acc;
      __syncthreads();
      if (k < 64) red[tid] += red[tid + 64];
      __syncthreads();
      if (k < 64) {
        float v = red[(half << 7) | k];
        v += __shfl_down(v, 32);
        v += __shfl_down(v, 16);
        v += __shfl_down(v, 8);
        v += __shfl_down(v, 4);
        v += __shfl_down(v, 2);
        v += __shfl_down(v, 1);
        if (k == 0) uh[(size_t)t * 128 + c] = v;
      }
    }

    grid_barrier(bar, (unsigned)(t + 1) * NWG);
  }
}

// ---------------------------------------------------------------------------
// cost_t = y_obs_t^T Q y_obs_t + u_t^T R u_t  (one block per t)
// ---------------------------------------------------------------------------
__global__ __launch_bounds__(256) void cost_kernel(const float* __restrict__ Q,
    const float* __restrict__ R, const float* __restrict__ yoh,
    const float* __restrict__ uh, float* __restrict__ out) {
  __shared__ float red[256];
  const int t = blockIdx.x;
  const int tid = threadIdx.x;
  const float* y = yoh + (size_t)t * 256;
  const float* u = uh + (size_t)t * 128;
  float acc;
  {
    const float* Qr = Q + (size_t)tid * 256;
    float qy = 0.f;
    for (int k = 0; k < 256; ++k) qy += Qr[k] * y[k];
    acc = qy * y[tid];
  }
  if (tid < 128) {
    const float* Rr = R + (size_t)tid * 128;
    float ru = 0.f;
    for (int k = 0; k < 128; ++k) ru += Rr[k] * u[k];
    acc += ru * u[tid];
  }
  red[tid] = acc;
  __syncthreads();
  if (tid < 128) red[tid] += red[tid + 128];
  __syncthreads();
  if (tid < 64) {
    float v = red[tid] + red[tid + 64];
    v += __shfl_down(v, 32);
    v += __shfl_down(v, 16);
    v += __shfl_down(v, 8);
    v += __shfl_down(v, 4);
    v += __shfl_down(v, 2);
    v += __shfl_down(v, 1);
    if (tid == 0) out[t] = v;
  }
}

// ---------------------------------------------------------------------------
extern "C" void kernel_launch(void* const* d_in, const int* in_sizes, int n_in,
                              void* d_out, int out_size, void* d_ws, size_t ws_size,
                              hipStream_t stream) {
  (void)in_sizes; (void)n_in; (void)out_size; (void)ws_size;
  const float* A = (const float*)d_in[0];    // 512x512
  const float* B = (const float*)d_in[1];    // 512x128
  const float* C = (const float*)d_in[2];    // 256x512
  const float* Q = (const float*)d_in[3];    // 256x256
  const float* R = (const float*)d_in[4];    // 128x128
  const float* K = (const float*)d_in[5];    // 128x256
  const float* MT = (const float*)d_in[6];   // 128x32x32x256
  const float* Phi = (const float*)d_in[7];  // 32x64
  const float* sm = (const float*)d_in[8];   // 32
  const float* x0 = (const float*)d_in[9];   // 512

  float* ws = (float*)d_ws;
  float* M2g = ws;              // 1048576
  float* W0 = M2g + 1048576;    // 32768
  float* W1m = W0 + 32768;      // 32768
  float* W0C = W1m + 32768;     // 65536
  float* KC = W0C + 65536;      // 65536
  float* KCA = KC + 65536;      // 65536
  float* KCB = KCA + 65536;     // 16384
  float* CAm = KCB + 16384;     // 131072
  float* CBm = CAm + 131072;    // 32768
  float* ABm = CBm + 32768;     // 65536
  float* A2 = ABm + 65536;      // 262144
  float* A4 = A2 + 262144;      // 262144
  float* A8 = A4 + 262144;      // 262144
  float* A16 = A8 + 262144;     // 262144
  float* A32 = A16 + 262144;    // 262144
  float* A33B = A32 + 262144;   // 65536
  float* xh = A33B + 65536;     // 1024*512
  float* uh = xh + 524288;      // 1024*128
  float* ynh = uh + 131072;     // 1024*256
  float* yoh = ynh + 262144;    // 1024*256
  float* dbuf = yoh + 262144;   // 2*512
  float* ytail = dbuf + 1024;   // 2*8192
  unsigned* bar = (unsigned*)(ytail + 16384);

  auto gemm = [&](const float* X, const float* Y, float* Z, int M, int N, int Kd) {
    dim3 g((N + 63) / 64, (M + 63) / 64);
    gemm_kernel<<<g, dim3(256), 0, stream>>>(X, Y, Z, M, N, Kd);
  };

  init_kernel<<<dim3(64), dim3(256), 0, stream>>>(x0, xh, dbuf, ytail, bar);
  m2_kernel<<<dim3(4096), dim3(256), 0, stream>>>(MT, sm, M2g);
  w01_kernel<<<dim3(128), dim3(256), 0, stream>>>(M2g, Phi, W0, W1m);

  gemm(W0, C, W0C, 128, 512, 256);
  gemm(K, C, KC, 128, 512, 256);
  gemm(KC, A, KCA, 128, 512, 512);
  gemm(KC, B, KCB, 128, 128, 512);
  gemm(C, A, CAm, 256, 512, 512);
  gemm(C, B, CBm, 256, 128, 512);
  gemm(A, B, ABm, 512, 128, 512);
  gemm(A, A, A2, 512, 512, 512);
  gemm(A2, A2, A4, 512, 512, 512);
  gemm(A4, A4, A8, 512, 512, 512);
  gemm(A8, A8, A16, 512, 512, 512);
  gemm(A16, A16, A32, 512, 512, 512);
  gemm(A32, ABm, A33B, 512, 128, 512);

  main_kernel<<<dim3(NWG), dim3(TPB), 0, stream>>>(
      A, B, C, x0, Phi, M2g, W0C, W1m, KC, KCA, KCB, CAm, CBm, A33B,
      xh, uh, ynh, yoh, dbuf, ytail, bar);

  cost_kernel<<<dim3(1024), dim3(256), 0, stream>>>(Q, R, yoh, uh, (float*)d_out);
}

// Round 2
// 22299.446 us; speedup vs baseline: 1.4044x; 1.4044x over previous
//
#include <hip/hip_runtime.h>

#define TPB 256
#define NWG 128

// ---------------------------------------------------------------------------
// Generic tiled fp32 GEMM: Z[M x N] = X[M x K] @ Y[K x N], row-major.
// ---------------------------------------------------------------------------
__global__ __launch_bounds__(256) void gemm_kernel(const float* __restrict__ X,
    const float* __restrict__ Y, float* __restrict__ Z, int M, int N, int Kd) {
  __shared__ float Xs[16][65];
  __shared__ float Ys[16][65];
  const int tx = threadIdx.x & 15;
  const int ty = threadIdx.x >> 4;
  const int mbase = blockIdx.y * 64;
  const int nbase = blockIdx.x * 64;
  float acc[4][4] = {};
  for (int k0 = 0; k0 < Kd; k0 += 16) {
#pragma unroll
    for (int r = 0; r < 4; ++r) {
      int idx = threadIdx.x + 256 * r;
      int mm = idx >> 4, kk = idx & 15;
      int gm = mbase + mm, gk = k0 + kk;
      Xs[kk][mm] = (gm < M && gk < Kd) ? X[(size_t)gm * Kd + gk] : 0.f;
      int nn = idx & 63, k2 = idx >> 6;
      int gn = nbase + nn, gk2 = k0 + k2;
      Ys[k2][nn] = (gk2 < Kd && gn < N) ? Y[(size_t)gk2 * N + gn] : 0.f;
    }
    __syncthreads();
#pragma unroll
    for (int kk = 0; kk < 16; ++kk) {
      float xv[4], yv[4];
#pragma unroll
      for (int a = 0; a < 4; ++a) xv[a] = Xs[kk][ty * 4 + a];
#pragma unroll
      for (int b = 0; b < 4; ++b) yv[b] = Ys[kk][tx * 4 + b];
#pragma unroll
      for (int a = 0; a < 4; ++a)
#pragma unroll
        for (int b = 0; b < 4; ++b) acc[a][b] += xv[a] * yv[b];
    }
    __syncthreads();
  }
#pragma unroll
  for (int a = 0; a < 4; ++a) {
    int gm = mbase + ty * 4 + a;
    if (gm < M) {
#pragma unroll
      for (int b = 0; b < 4; ++b) {
        int gn = nbase + tx * 4 + b;
        if (gn < N) Z[(size_t)gm * N + gn] = acc[a][b];
      }
    }
  }
}

// ---------------------------------------------------------------------------
__global__ __launch_bounds__(256) void m2_kernel(const float* __restrict__ MT,
    const float* __restrict__ sm, float* __restrict__ M2g) {
  int idx = blockIdx.x * 256 + threadIdx.x;  // c*8192 + i*256 + q
  if (idx >= 128 * 32 * 256) return;
  int q = idx & 255;
  int ci = idx >> 8;
  const float* base = MT + (size_t)ci * 32 * 256 + q;
  float acc = 0.f;
#pragma unroll
  for (int j = 0; j < 32; ++j) acc += base[j * 256] * sm[j];
  M2g[idx] = acc;
}

// ---------------------------------------------------------------------------
__global__ __launch_bounds__(256) void w01_kernel(const float* __restrict__ M2g,
    const float* __restrict__ Phi, float* __restrict__ W0, float* __restrict__ W1m) {
  int idx = blockIdx.x * 256 + threadIdx.x;  // c*256 + q
  if (idx >= 128 * 256) return;
  int q = idx & 255, c = idx >> 8;
  float a0 = 0.f, a1 = 0.f;
#pragma unroll
  for (int i = 0; i < 32; ++i) {
    float m = M2g[((size_t)(c * 32 + i)) * 256 + q];
    a0 += m * Phi[i * 64];
    a1 += m * Phi[i * 64 + 1];
  }
  W0[idx] = a0;
  W1m[idx] = a1;
}

// ---------------------------------------------------------------------------
__global__ void init_kernel(const float* __restrict__ x0, float* __restrict__ xh,
    float* __restrict__ dbuf, float* __restrict__ ytail, unsigned* __restrict__ arr) {
  int tid = blockIdx.x * 256 + threadIdx.x;
  if (tid < 512) {
    xh[tid] = x0[tid];
    dbuf[tid] = x0[tid];
    dbuf[512 + tid] = 0.f;
  }
  if (tid < 16384) ytail[tid] = 0.f;
  if (tid < NWG * 32) arr[tid] = 0u;
}

// ---------------------------------------------------------------------------
// Flat grid barrier: per-WG padded arrive slot (release store), all WGs poll
// all slots with relaxed agent loads. No RMW, no line ping-pong.
// ---------------------------------------------------------------------------
__device__ __forceinline__ void grid_barrier(unsigned* __restrict__ arr, int bid,
                                             int tid, unsigned phase) {
  __syncthreads();
  if (tid == 0) {
    __threadfence();  // release: make this WG's phase writes visible device-wide
    __hip_atomic_store(arr + bid * 32, phase, __ATOMIC_RELEASE, __HIP_MEMORY_SCOPE_AGENT);
  }
  if (tid < NWG) {
    while (__hip_atomic_load(arr + tid * 32, __ATOMIC_RELAXED, __HIP_MEMORY_SCOPE_AGENT) < phase) {
      __builtin_amdgcn_s_sleep(1);
    }
  }
  __syncthreads();
  if (tid == 0) __threadfence();  // acquire: invalidate stale cached lines
  __syncthreads();
}

// ---------------------------------------------------------------------------
__device__ __forceinline__ float dot512(const float* __restrict__ a,
                                        const float* __restrict__ b, int ls) {
  const float4* a4 = (const float4*)a;
  const float4* b4 = (const float4*)b;
  float s = 0.f;
#pragma unroll
  for (int it = 0; it < 16; ++it) {
    float4 av = a4[it * 8 + ls];
    float4 bv = b4[it * 8 + ls];
    s += av.x * bv.x + av.y * bv.y + av.z * bv.z + av.w * bv.w;
  }
  return s;
}
__device__ __forceinline__ float dot128(const float* __restrict__ a,
                                        const float* __restrict__ b, int ls) {
  const float4* a4 = (const float4*)a;
  const float4* b4 = (const float4*)b;
  float s = 0.f;
#pragma unroll
  for (int it = 0; it < 4; ++it) {
    float4 av = a4[it * 8 + ls];
    float4 bv = b4[it * 8 + ls];
    s += av.x * bv.x + av.y * bv.y + av.z * bv.z + av.w * bv.w;
  }
  return s;
}

// ---------------------------------------------------------------------------
// Persistent main loop, one barrier per step. Role-split workgroups:
//   WGs 0..47  : matvecs (x_t, y_obs_t, y_nat_t, d_{t+1}) — 32 8-lane groups each
//   WGs 48..63 : ytail2_{t+1}[i,q] = sum_{j=2..63} Phi[i,j] y_nat_{t+1-j}[q]
//   WGs 64..127: u_t for c = (bid-64)*2 + {0,1}; M2 c-slice pinned in LDS
// ---------------------------------------------------------------------------
__global__ __launch_bounds__(TPB, 1) void main_kernel(
    const float* __restrict__ A, const float* __restrict__ B, const float* __restrict__ C,
    const float* __restrict__ x0, const float* __restrict__ Phi,
    const float* __restrict__ M2g, const float* __restrict__ W0C,
    const float* __restrict__ W1m, const float* __restrict__ KC,
    const float* __restrict__ KCA, const float* __restrict__ KCB,
    const float* __restrict__ CA, const float* __restrict__ CB,
    const float* __restrict__ A33B,
    float* __restrict__ xh, float* __restrict__ uh, float* __restrict__ ynh,
    float* __restrict__ yoh, float* __restrict__ dbuf, float* __restrict__ ytail,
    unsigned* __restrict__ arr) {
  __shared__ float m2s[16384];
  __shared__ float red[TPB];
  const int bid = blockIdx.x;
  const int tid = threadIdx.x;

  if (bid >= 64) {
    const int c0 = (bid - 64) * 2;
    for (int i = tid; i < 16384; i += TPB) m2s[i] = M2g[(size_t)c0 * 8192 + i];
  }
  __syncthreads();

#pragma unroll 1
  for (int t = 0; t < 1024; ++t) {
    const float* xprev = (t > 0) ? (xh + (size_t)(t - 1) * 512) : x0;
    const float* uprev = uh + (size_t)(t > 0 ? t - 1 : 0) * 128;
    const float* dcur = dbuf + (t & 1) * 512;
    float* dnext = dbuf + ((t + 1) & 1) * 512;
    const float* ytcur = ytail + (t & 1) * 8192;
    float* ytnext = ytail + ((t + 1) & 1) * 8192;

    if (bid < 48) {
      // ---- matvec tasks: 8-lane groups, float4 loads ----
      const int grp = (bid << 5) | (tid >> 3);  // 0..1535
      const int ls = tid & 7;
      float acc = 0.f;
      float* dstp = nullptr;
      if (grp < 512) {  // x_t[d]
        if (t > 0) {
          const int d = grp;
          acc = dot512(A + (size_t)d * 512, xprev, ls) +
                dot128(B + (size_t)d * 128, uprev, ls);
          dstp = xh + (size_t)t * 512 + d;
        }
      } else if (grp < 768) {  // y_obs_t[p]
        const int p = grp - 512;
        if (t == 0) {
          acc = dot512(C + (size_t)p * 512, x0, ls);
        } else {
          acc = dot512(CA + (size_t)p * 512, xprev, ls) +
                dot128(CB + (size_t)p * 128, uprev, ls);
        }
        dstp = yoh + (size_t)t * 256 + p;
      } else if (grp < 1024) {  // y_nat_t[p] = C d_t
        const int p = grp - 768;
        acc = dot512(C + (size_t)p * 512, dcur, ls);
        dstp = ynh + (size_t)t * 256 + p;
      } else {  // d_{t+1}[d]
        const int d = grp - 1024;
        acc = dot512(A + (size_t)d * 512, dcur, ls);
        if (t >= 33)
          acc += dot128(A33B + (size_t)d * 128, uh + (size_t)(t - 33) * 128, ls);
        dstp = dnext + d;
      }
      acc += __shfl_down(acc, 4);
      acc += __shfl_down(acc, 2);
      acc += __shfl_down(acc, 1);
      if (ls == 0 && dstp) *dstp = acc;
    } else if (bid < 64) {
      // ---- ytail2_{t+1}[i][q] ----
      int base = ((bid - 48) << 8) | tid;  // 0..4095
#pragma unroll
      for (int rr = 0; rr < 2; ++rr) {
        int idx = base + rr * 4096;
        int i = idx >> 8, q = idx & 255;
        float acc = 0.f;
        int jmax = (t + 1 < 64) ? (t + 1) : 63;
        for (int j = 2; j <= jmax; ++j)
          acc += Phi[(i << 6) | j] * ynh[(size_t)(t + 1 - j) * 256 + q];
        ytnext[idx] = acc;
      }
    } else {
      // ---- u_t[c0 + (tid>>7)] ----
      const int c0 = (bid - 64) * 2;
      const int half = tid >> 7;
      const int k = tid & 127;
      const int c = c0 + half;
      float acc = 0.f;
      const float* m2c = m2s + half * 8192;
#pragma unroll 8
      for (int n = 0; n < 64; ++n) {
        int iq = k + (n << 7);
        acc += m2c[iq] * ytcur[iq];
      }
      const float* w0cr = W0C + (size_t)c * 512;
      for (int kk = k; kk < 512; kk += 128) acc += w0cr[kk] * dcur[kk];
      if (t == 0) {
        const float* kcr = KC + (size_t)c * 512;
        for (int kk = k; kk < 512; kk += 128) acc -= kcr[kk] * x0[kk];
      } else {
        const float* kcar = KCA + (size_t)c * 512;
        for (int kk = k; kk < 512; kk += 128) acc -= kcar[kk] * xprev[kk];
        acc -= KCB[(size_t)c * 128 + k] * uprev[k];
        const float* ynp = ynh + (size_t)(t - 1) * 256;
        const float* w1r = W1m + (size_t)c * 256;
        acc += w1r[k] * ynp[k] + w1r[k + 128] * ynp[k + 128];
      }
      red[tid] = acc;
      __syncthreads();
      if (k < 64) red[tid] += red[tid + 64];
      __syncthreads();
      if (k < 64) {
        float v = red[(half << 7) | k];
        v += __shfl_down(v, 32);
        v += __shfl_down(v, 16);
        v += __shfl_down(v, 8);
        v += __shfl_down(v, 4);
        v += __shfl_down(v, 2);
        v += __shfl_down(v, 1);
        if (k == 0) uh[(size_t)t * 128 + c] = v;
      }
    }

    grid_barrier(arr, bid, tid, (unsigned)(t + 1));
  }
}

// ---------------------------------------------------------------------------
__global__ __launch_bounds__(256) void cost_kernel(const float* __restrict__ Q,
    const float* __restrict__ R, const float* __restrict__ yoh,
    const float* __restrict__ uh, float* __restrict__ out) {
  __shared__ float red[256];
  const int t = blockIdx.x;
  const int tid = threadIdx.x;
  const float* y = yoh + (size_t)t * 256;
  const float* u = uh + (size_t)t * 128;
  float acc;
  {
    const float* Qr = Q + (size_t)tid * 256;
    float qy = 0.f;
    for (int k = 0; k < 256; ++k) qy += Qr[k] * y[k];
    acc = qy * y[tid];
  }
  if (tid < 128) {
    const float* Rr = R + (size_t)tid * 128;
    float ru = 0.f;
    for (int k = 0; k < 128; ++k) ru += Rr[k] * u[k];
    acc += ru * u[tid];
  }
  red[tid] = acc;
  __syncthreads();
  if (tid < 128) red[tid] += red[tid + 128];
  __syncthreads();
  if (tid < 64) {
    float v = red[tid] + red[tid + 64];
    v += __shfl_down(v, 32);
    v += __shfl_down(v, 16);
    v += __shfl_down(v, 8);
    v += __shfl_down(v, 4);
    v += __shfl_down(v, 2);
    v += __shfl_down(v, 1);
    if (tid == 0) out[t] = v;
  }
}

// ---------------------------------------------------------------------------
extern "C" void kernel_launch(void* const* d_in, const int* in_sizes, int n_in,
                              void* d_out, int out_size, void* d_ws, size_t ws_size,
                              hipStream_t stream) {
  (void)in_sizes; (void)n_in; (void)out_size; (void)ws_size;
  const float* A = (const float*)d_in[0];
  const float* B = (const float*)d_in[1];
  const float* C = (const float*)d_in[2];
  const float* Q = (const float*)d_in[3];
  const float* R = (const float*)d_in[4];
  const float* K = (const float*)d_in[5];
  const float* MT = (const float*)d_in[6];
  const float* Phi = (const float*)d_in[7];
  const float* sm = (const float*)d_in[8];
  const float* x0 = (const float*)d_in[9];

  float* ws = (float*)d_ws;
  float* M2g = ws;              // 1048576
  float* W0 = M2g + 1048576;    // 32768
  float* W1m = W0 + 32768;      // 32768
  float* W0C = W1m + 32768;     // 65536
  float* KC = W0C + 65536;      // 65536
  float* KCA = KC + 65536;      // 65536
  float* KCB = KCA + 65536;     // 16384
  float* CAm = KCB + 16384;     // 131072
  float* CBm = CAm + 131072;    // 32768
  float* ABm = CBm + 32768;     // 65536
  float* A2 = ABm + 65536;      // 262144
  float* A4 = A2 + 262144;      // 262144
  float* A8 = A4 + 262144;      // 262144
  float* A16 = A8 + 262144;     // 262144
  float* A32 = A16 + 262144;    // 262144
  float* A33B = A32 + 262144;   // 65536
  float* xh = A33B + 65536;     // 1024*512
  float* uh = xh + 524288;      // 1024*128
  float* ynh = uh + 131072;     // 1024*256
  float* yoh = ynh + 262144;    // 1024*256
  float* dbuf = yoh + 262144;   // 2*512
  float* ytail = dbuf + 1024;   // 2*8192
  unsigned* arr = (unsigned*)(ytail + 16384);  // NWG*32 u32

  auto gemm = [&](const float* X, const float* Y, float* Z, int M, int N, int Kd) {
    dim3 g((N + 63) / 64, (M + 63) / 64);
    gemm_kernel<<<g, dim3(256), 0, stream>>>(X, Y, Z, M, N, Kd);
  };

  init_kernel<<<dim3(64), dim3(256), 0, stream>>>(x0, xh, dbuf, ytail, arr);
  m2_kernel<<<dim3(4096), dim3(256), 0, stream>>>(MT, sm, M2g);
  w01_kernel<<<dim3(128), dim3(256), 0, stream>>>(M2g, Phi, W0, W1m);

  gemm(W0, C, W0C, 128, 512, 256);
  gemm(K, C, KC, 128, 512, 256);
  gemm(KC, A, KCA, 128, 512, 512);
  gemm(KC, B, KCB, 128, 128, 512);
  gemm(C, A, CAm, 256, 512, 512);
  gemm(C, B, CBm, 256, 128, 512);
  gemm(A, B, ABm, 512, 128, 512);
  gemm(A, A, A2, 512, 512, 512);
  gemm(A2, A2, A4, 512, 512, 512);
  gemm(A4, A4, A8, 512, 512, 512);
  gemm(A8, A8, A16, 512, 512, 512);
  gemm(A16, A16, A32, 512, 512, 512);
  gemm(A32, ABm, A33B, 512, 128, 512);

  main_kernel<<<dim3(NWG), dim3(TPB), 0, stream>>>(
      A, B, C, x0, Phi, M2g, W0C, W1m, KC, KCA, KCB, CAm, CBm, A33B,
      xh, uh, ynh, yoh, dbuf, ytail, arr);

  cost_kernel<<<dim3(1024), dim3(256), 0, stream>>>(Q, R, yoh, uh, (float*)d_out);
}

// Round 3
// 9294.205 us; speedup vs baseline: 3.3695x; 2.3993x over previous
//
#include <hip/hip_runtime.h>

#define TPB 256
#define NWG 120

// ---------------------------------------------------------------------------
// Coherent (agent-scope, L1/L2-bypassing) access helpers. Relaxed atomics
// compile to global_load/store with sc1 -> served at the Infinity Cache
// coherence point. No fences, no buffer_wbl2/buffer_inv anywhere.
// ---------------------------------------------------------------------------
__device__ __forceinline__ void cst(float* p, float v) {
  __hip_atomic_store(p, v, __ATOMIC_RELAXED, __HIP_MEMORY_SCOPE_AGENT);
}
__device__ __forceinline__ float cld(const float* p) {
  return __hip_atomic_load(p, __ATOMIC_RELAXED, __HIP_MEMORY_SCOPE_AGENT);
}
__device__ __forceinline__ float2 cld2(const float* p) {
  unsigned long long u = __hip_atomic_load(
      reinterpret_cast<const unsigned long long*>(p), __ATOMIC_RELAXED,
      __HIP_MEMORY_SCOPE_AGENT);
  float2 v;
  __builtin_memcpy(&v, &u, 8);
  return v;
}

// Matrix row: plain cached loads (constants, L2-resident). Vector: coherent.
__device__ __forceinline__ float dot512c(const float* __restrict__ m,
                                         const float* __restrict__ v, int ls) {
  const float2* m2 = reinterpret_cast<const float2*>(m);
  float s = 0.f;
#pragma unroll
  for (int it = 0; it < 32; ++it) {
    int e = (it << 3) | ls;
    float2 a = m2[e];
    float2 b = cld2(v + (e << 1));
    s = fmaf(a.x, b.x, s);
    s = fmaf(a.y, b.y, s);
  }
  return s;
}
__device__ __forceinline__ float dot128c(const float* __restrict__ m,
                                         const float* __restrict__ v, int ls) {
  const float2* m2 = reinterpret_cast<const float2*>(m);
  float s = 0.f;
#pragma unroll
  for (int it = 0; it < 8; ++it) {
    int e = (it << 3) | ls;
    float2 a = m2[e];
    float2 b = cld2(v + (e << 1));
    s = fmaf(a.x, b.x, s);
    s = fmaf(a.y, b.y, s);
  }
  return s;
}

// ---------------------------------------------------------------------------
// Grid barrier with NO cache maintenance: per-wave vmcnt drain (sc1 stores
// are ack'd at the coherence point), relaxed flag store, relaxed poll.
// ---------------------------------------------------------------------------
__device__ __forceinline__ void grid_barrier(unsigned* __restrict__ arr,
                                             int bid, int tid, unsigned phase) {
  asm volatile("s_waitcnt vmcnt(0)" ::: "memory");
  __syncthreads();
  if (tid == 0)
    __hip_atomic_store(arr + (bid << 5), phase, __ATOMIC_RELAXED,
                       __HIP_MEMORY_SCOPE_AGENT);
  if (tid < NWG) {
    while (__hip_atomic_load(arr + (tid << 5), __ATOMIC_RELAXED,
                             __HIP_MEMORY_SCOPE_AGENT) < phase)
      __builtin_amdgcn_s_sleep(1);
  }
  __atomic_signal_fence(__ATOMIC_SEQ_CST);
  __syncthreads();
}

// ---------------------------------------------------------------------------
// Generic tiled fp32 GEMM: Z[M x N] = X[M x K] @ Y[K x N], row-major.
// ---------------------------------------------------------------------------
__global__ __launch_bounds__(256) void gemm_kernel(const float* __restrict__ X,
    const float* __restrict__ Y, float* __restrict__ Z, int M, int N, int Kd) {
  __shared__ float Xs[16][65];
  __shared__ float Ys[16][65];
  const int tx = threadIdx.x & 15;
  const int ty = threadIdx.x >> 4;
  const int mbase = blockIdx.y * 64;
  const int nbase = blockIdx.x * 64;
  float acc[4][4] = {};
  for (int k0 = 0; k0 < Kd; k0 += 16) {
#pragma unroll
    for (int r = 0; r < 4; ++r) {
      int idx = threadIdx.x + 256 * r;
      int mm = idx >> 4, kk = idx & 15;
      int gm = mbase + mm, gk = k0 + kk;
      Xs[kk][mm] = (gm < M && gk < Kd) ? X[(size_t)gm * Kd + gk] : 0.f;
      int nn = idx & 63, k2 = idx >> 6;
      int gn = nbase + nn, gk2 = k0 + k2;
      Ys[k2][nn] = (gk2 < Kd && gn < N) ? Y[(size_t)gk2 * N + gn] : 0.f;
    }
    __syncthreads();
#pragma unroll
    for (int kk = 0; kk < 16; ++kk) {
      float xv[4], yv[4];
#pragma unroll
      for (int a = 0; a < 4; ++a) xv[a] = Xs[kk][ty * 4 + a];
#pragma unroll
      for (int b = 0; b < 4; ++b) yv[b] = Ys[kk][tx * 4 + b];
#pragma unroll
      for (int a = 0; a < 4; ++a)
#pragma unroll
        for (int b = 0; b < 4; ++b) acc[a][b] += xv[a] * yv[b];
    }
    __syncthreads();
  }
#pragma unroll
  for (int a = 0; a < 4; ++a) {
    int gm = mbase + ty * 4 + a;
    if (gm < M) {
#pragma unroll
      for (int b = 0; b < 4; ++b) {
        int gn = nbase + tx * 4 + b;
        if (gn < N) Z[(size_t)gm * N + gn] = acc[a][b];
      }
    }
  }
}

// ---------------------------------------------------------------------------
__global__ __launch_bounds__(256) void m2_kernel(const float* __restrict__ MT,
    const float* __restrict__ sm, float* __restrict__ M2g) {
  int idx = blockIdx.x * 256 + threadIdx.x;  // c*8192 + i*256 + q
  if (idx >= 128 * 32 * 256) return;
  int q = idx & 255;
  int ci = idx >> 8;
  const float* base = MT + (size_t)ci * 32 * 256 + q;
  float acc = 0.f;
#pragma unroll
  for (int j = 0; j < 32; ++j) acc += base[j * 256] * sm[j];
  M2g[idx] = acc;
}

// ---------------------------------------------------------------------------
__global__ __launch_bounds__(256) void w01_kernel(const float* __restrict__ M2g,
    const float* __restrict__ Phi, float* __restrict__ W0, float* __restrict__ W1m) {
  int idx = blockIdx.x * 256 + threadIdx.x;  // c*256 + q
  if (idx >= 128 * 256) return;
  int q = idx & 255, c = idx >> 8;
  float a0 = 0.f, a1 = 0.f;
#pragma unroll
  for (int i = 0; i < 32; ++i) {
    float m = M2g[((size_t)(c * 32 + i)) * 256 + q];
    a0 += m * Phi[i * 64];
    a1 += m * Phi[i * 64 + 1];
  }
  W0[idx] = a0;
  W1m[idx] = a1;
}

// ---------------------------------------------------------------------------
__global__ void init_kernel(const float* __restrict__ x0, float* __restrict__ xh,
    float* __restrict__ dbuf, float* __restrict__ ytail, unsigned* __restrict__ arr) {
  int tid = blockIdx.x * 256 + threadIdx.x;
  if (tid < 512) {
    xh[tid] = x0[tid];
    dbuf[tid] = x0[tid];
    dbuf[512 + tid] = 0.f;
  }
  if (tid < 16384) ytail[tid] = 0.f;
  if (tid < NWG * 32) arr[tid] = 0u;
}

// ---------------------------------------------------------------------------
// Persistent main loop, one barrier per step. Roles:
//   WG  0..15 : x_t[d]      = A x_{t-1} + B u_{t-1}        (512 8-lane groups)
//   WG 16..23 : y_nat_t[p]  = C d_t                        (256 groups)
//   WG 24..39 : d_{t+1}[d]  = A d_t + A33B u_{t-33}        (512 groups)
//   WG 40..55 : ytail2_{t+1}[i,q] = sum_{j>=2} Phi[i,j] y_nat_{t+1-j}[q]
//   WG 56..119: u_t[c] ; M2 c-slice (2 rows) pinned in LDS
// y_obs / cost are NOT in the loop (parallel epilogue).
// ---------------------------------------------------------------------------
__global__ __launch_bounds__(TPB, 1) void main_kernel(
    const float* __restrict__ A, const float* __restrict__ B,
    const float* __restrict__ C, const float* __restrict__ x0,
    const float* __restrict__ Phi, const float* __restrict__ M2g,
    const float* __restrict__ W0C, const float* __restrict__ W1m,
    const float* __restrict__ KC, const float* __restrict__ KCA,
    const float* __restrict__ KCB, const float* __restrict__ A33B,
    float* __restrict__ xh, float* __restrict__ uh, float* __restrict__ ynh,
    float* __restrict__ dbuf, float* __restrict__ ytail,
    unsigned* __restrict__ arr) {
  __shared__ float m2s[16384];
  __shared__ float red[TPB];
  const int bid = blockIdx.x;
  const int tid = threadIdx.x;

  if (bid >= 56) {
    const int c0 = (bid - 56) * 2;
    for (int i = tid; i < 16384; i += TPB) m2s[i] = M2g[(size_t)c0 * 8192 + i];
  }
  __syncthreads();

  const int grp8 = tid >> 3;
  const int ls = tid & 7;

#pragma unroll 1
  for (int t = 0; t < 1024; ++t) {
    const float* xprev = xh + (size_t)(t > 0 ? t - 1 : 0) * 512;
    const float* uprev = uh + (size_t)(t > 0 ? t - 1 : 0) * 128;
    const float* dcur = dbuf + (t & 1) * 512;
    float* dnext = dbuf + ((t + 1) & 1) * 512;
    const float* ytcur = ytail + (t & 1) * 8192;
    float* ytnext = ytail + ((t + 1) & 1) * 8192;

    if (bid < 16) {
      // ---- x_t ----
      if (t > 0) {
        const int d = (bid << 5) | grp8;
        float acc = dot512c(A + (size_t)d * 512, xprev, ls) +
                    dot128c(B + (size_t)d * 128, uprev, ls);
        acc += __shfl_down(acc, 4);
        acc += __shfl_down(acc, 2);
        acc += __shfl_down(acc, 1);
        if (ls == 0) cst(xh + (size_t)t * 512 + d, acc);
      }
    } else if (bid < 24) {
      // ---- y_nat_t ----
      const int p = ((bid - 16) << 5) | grp8;
      float acc = dot512c(C + (size_t)p * 512, dcur, ls);
      acc += __shfl_down(acc, 4);
      acc += __shfl_down(acc, 2);
      acc += __shfl_down(acc, 1);
      if (ls == 0) cst(ynh + (size_t)t * 256 + p, acc);
    } else if (bid < 40) {
      // ---- d_{t+1} ----
      const int d = ((bid - 24) << 5) | grp8;
      float acc = dot512c(A + (size_t)d * 512, dcur, ls);
      if (t >= 33)
        acc += dot128c(A33B + (size_t)d * 128, uh + (size_t)(t - 33) * 128, ls);
      acc += __shfl_down(acc, 4);
      acc += __shfl_down(acc, 2);
      acc += __shfl_down(acc, 1);
      if (ls == 0) cst(dnext + d, acc);
    } else if (bid < 56) {
      // ---- ytail2_{t+1}: each thread -> (i0,q) and (i0+16,q) ----
      const int base = ((bid - 40) << 8) | tid;  // 0..4095
      const int q = base & 255;
      const int i0 = base >> 8;  // 0..15
      const float* phr0 = Phi + i0 * 64;
      const float* phr1 = Phi + (i0 + 16) * 64;
      float a0 = 0.f, a1 = 0.f;
      const int jmax = (t + 1 < 64) ? (t + 1) : 63;
      for (int j = 2; j <= jmax; ++j) {
        float y = cld(ynh + (size_t)(t + 1 - j) * 256 + q);
        a0 = fmaf(phr0[j], y, a0);
        a1 = fmaf(phr1[j], y, a1);
      }
      cst(ytnext + base, a0);
      cst(ytnext + base + 4096, a1);
    } else {
      // ---- u_t ----
      const int c0 = (bid - 56) * 2;
      const int half = tid >> 7;
      const int k = tid & 127;
      const int c = c0 + half;
      float acc = 0.f;
      const float* m2c = m2s + (half << 13);
#pragma unroll 8
      for (int n = 0; n < 64; ++n) {
        int iq = k + (n << 7);
        acc = fmaf(m2c[iq], cld(ytcur + iq), acc);
      }
      const float* w0cr = W0C + (size_t)c * 512;
      for (int kk = k; kk < 512; kk += 128) acc = fmaf(w0cr[kk], cld(dcur + kk), acc);
      if (t == 0) {
        const float* kcr = KC + (size_t)c * 512;
        for (int kk = k; kk < 512; kk += 128) acc -= kcr[kk] * x0[kk];
      } else {
        const float* kcar = KCA + (size_t)c * 512;
        for (int kk = k; kk < 512; kk += 128) acc -= kcar[kk] * cld(xprev + kk);
        acc -= KCB[(size_t)c * 128 + k] * cld(uprev + k);
        const float* ynp = ynh + (size_t)(t - 1) * 256;
        const float* w1r = W1m + (size_t)c * 256;
        acc = fmaf(w1r[k], cld(ynp + k), acc);
        acc = fmaf(w1r[k + 128], cld(ynp + k + 128), acc);
      }
      red[tid] = acc;
      __syncthreads();
      if (k < 64) red[tid] += red[tid + 64];
      __syncthreads();
      if (k < 64) {
        float v = red[(half << 7) | k];
        v += __shfl_down(v, 32);
        v += __shfl_down(v, 16);
        v += __shfl_down(v, 8);
        v += __shfl_down(v, 4);
        v += __shfl_down(v, 2);
        v += __shfl_down(v, 1);
        if (k == 0) cst(uh + (size_t)t * 128 + c, v);
      }
    }

    grid_barrier(arr, bid, tid, (unsigned)(t + 1));
  }
}

// ---------------------------------------------------------------------------
// Epilogue (parallel over t): y_obs_t = CA x_{t-1} + CB u_{t-1} (t=0: C x0),
// cost_t = y^T Q y + u^T R u. Reads xh/uh coherently (sc1 stores don't
// refresh stale L2 lines left by the harness poison).
// ---------------------------------------------------------------------------
__global__ __launch_bounds__(256) void cost_kernel(const float* __restrict__ CA,
    const float* __restrict__ CB, const float* __restrict__ C,
    const float* __restrict__ Q, const float* __restrict__ R,
    const float* __restrict__ x0, const float* __restrict__ xh,
    const float* __restrict__ uh, float* __restrict__ out) {
  __shared__ float xs[512];
  __shared__ float us[128];
  __shared__ float up[128];
  __shared__ float yo[256];
  __shared__ float red[256];
  const int t = blockIdx.x;
  const int tid = threadIdx.x;
  if (t > 0) {
    float2 v = cld2(xh + (size_t)(t - 1) * 512 + tid * 2);
    xs[tid * 2] = v.x;
    xs[tid * 2 + 1] = v.y;
    if (tid >= 128) up[tid - 128] = cld(uh + (size_t)(t - 1) * 128 + (tid - 128));
  } else {
    xs[tid] = x0[tid];
    xs[tid + 256] = x0[tid + 256];
  }
  if (tid < 128) us[tid] = cld(uh + (size_t)t * 128 + tid);
  __syncthreads();

  float acc = 0.f;
  if (t == 0) {
    const float* Cr = C + (size_t)tid * 512;
    for (int k = 0; k < 512; ++k) acc = fmaf(Cr[k], xs[k], acc);
  } else {
    const float* CAr = CA + (size_t)tid * 512;
    for (int k = 0; k < 512; ++k) acc = fmaf(CAr[k], xs[k], acc);
    const float* CBr = CB + (size_t)tid * 128;
    for (int k = 0; k < 128; ++k) acc = fmaf(CBr[k], up[k], acc);
  }
  yo[tid] = acc;
  __syncthreads();

  const float* Qr = Q + (size_t)tid * 256;
  float qy = 0.f;
  for (int k = 0; k < 256; ++k) qy = fmaf(Qr[k], yo[k], qy);
  float cc = qy * yo[tid];
  if (tid < 128) {
    const float* Rr = R + (size_t)tid * 128;
    float ru = 0.f;
    for (int k = 0; k < 128; ++k) ru = fmaf(Rr[k], us[k], ru);
    cc += ru * us[tid];
  }
  red[tid] = cc;
  __syncthreads();
  if (tid < 128) red[tid] += red[tid + 128];
  __syncthreads();
  if (tid < 64) {
    float v = red[tid] + red[tid + 64];
    v += __shfl_down(v, 32);
    v += __shfl_down(v, 16);
    v += __shfl_down(v, 8);
    v += __shfl_down(v, 4);
    v += __shfl_down(v, 2);
    v += __shfl_down(v, 1);
    if (tid == 0) out[t] = v;
  }
}

// ---------------------------------------------------------------------------
extern "C" void kernel_launch(void* const* d_in, const int* in_sizes, int n_in,
                              void* d_out, int out_size, void* d_ws, size_t ws_size,
                              hipStream_t stream) {
  (void)in_sizes; (void)n_in; (void)out_size; (void)ws_size;
  const float* A = (const float*)d_in[0];
  const float* B = (const float*)d_in[1];
  const float* C = (const float*)d_in[2];
  const float* Q = (const float*)d_in[3];
  const float* R = (const float*)d_in[4];
  const float* K = (const float*)d_in[5];
  const float* MT = (const float*)d_in[6];
  const float* Phi = (const float*)d_in[7];
  const float* sm = (const float*)d_in[8];
  const float* x0 = (const float*)d_in[9];

  float* ws = (float*)d_ws;
  float* M2g = ws;              // 1048576
  float* W0 = M2g + 1048576;    // 32768
  float* W1m = W0 + 32768;      // 32768
  float* W0C = W1m + 32768;     // 65536
  float* KC = W0C + 65536;      // 65536
  float* KCA = KC + 65536;      // 65536
  float* KCB = KCA + 65536;     // 16384
  float* CAm = KCB + 16384;     // 131072
  float* CBm = CAm + 131072;    // 32768
  float* ABm = CBm + 32768;     // 65536
  float* A2 = ABm + 65536;      // 262144
  float* A4 = A2 + 262144;      // 262144
  float* A8 = A4 + 262144;      // 262144
  float* A16 = A8 + 262144;     // 262144
  float* A32 = A16 + 262144;    // 262144
  float* A33B = A32 + 262144;   // 65536
  float* xh = A33B + 65536;     // 1024*512
  float* uh = xh + 524288;      // 1024*128
  float* ynh = uh + 131072;     // 1024*256
  float* dbuf = ynh + 262144;   // 2*512
  float* ytail = dbuf + 1024;   // 2*8192
  unsigned* arr = (unsigned*)(ytail + 16384);  // NWG*32 u32

  auto gemm = [&](const float* X, const float* Y, float* Z, int M, int N, int Kd) {
    dim3 g((N + 63) / 64, (M + 63) / 64);
    gemm_kernel<<<g, dim3(256), 0, stream>>>(X, Y, Z, M, N, Kd);
  };

  init_kernel<<<dim3(64), dim3(256), 0, stream>>>(x0, xh, dbuf, ytail, arr);
  m2_kernel<<<dim3(4096), dim3(256), 0, stream>>>(MT, sm, M2g);
  w01_kernel<<<dim3(128), dim3(256), 0, stream>>>(M2g, Phi, W0, W1m);

  gemm(W0, C, W0C, 128, 512, 256);
  gemm(K, C, KC, 128, 512, 256);
  gemm(KC, A, KCA, 128, 512, 512);
  gemm(KC, B, KCB, 128, 128, 512);
  gemm(C, A, CAm, 256, 512, 512);
  gemm(C, B, CBm, 256, 128, 512);
  gemm(A, B, ABm, 512, 128, 512);
  gemm(A, A, A2, 512, 512, 512);
  gemm(A2, A2, A4, 512, 512, 512);
  gemm(A4, A4, A8, 512, 512, 512);
  gemm(A8, A8, A16, 512, 512, 512);
  gemm(A16, A16, A32, 512, 512, 512);
  gemm(A32, ABm, A33B, 512, 128, 512);

  main_kernel<<<dim3(NWG), dim3(TPB), 0, stream>>>(
      A, B, C, x0, Phi, M2g, W0C, W1m, KC, KCA, KCB, A33B,
      xh, uh, ynh, dbuf, ytail, arr);

  cost_kernel<<<dim3(1024), dim3(256), 0, stream>>>(CAm, CBm, C, Q, R, x0, xh, uh,
                                                    (float*)d_out);
}

// Round 4
// 7942.419 us; speedup vs baseline: 3.9430x; 1.1702x over previous
//
#include <hip/hip_runtime.h>

#define TPB 256
#define NWG 104

// ---------------------------------------------------------------------------
// Coherent (agent-scope, MALL-served) access helpers. Relaxed atomics compile
// to sc1 global loads/stores: bypass non-coherent L1/L2, no fences needed.
// ---------------------------------------------------------------------------
__device__ __forceinline__ void cst(float* p, float v) {
  __hip_atomic_store(p, v, __ATOMIC_RELAXED, __HIP_MEMORY_SCOPE_AGENT);
}
__device__ __forceinline__ float cld(const float* p) {
  return __hip_atomic_load(p, __ATOMIC_RELAXED, __HIP_MEMORY_SCOPE_AGENT);
}
__device__ __forceinline__ float2 cld2(const float* p) {
  unsigned long long u = __hip_atomic_load(
      reinterpret_cast<const unsigned long long*>(p), __ATOMIC_RELAXED,
      __HIP_MEMORY_SCOPE_AGENT);
  float2 v;
  __builtin_memcpy(&v, &u, 8);
  return v;
}

// Stage global (coherent) -> LDS, coalesced 8B per lane.
__device__ __forceinline__ void stage512(float* dst, const float* src, int tid) {
  float2 v = cld2(src + (tid << 1));
  dst[tid << 1] = v.x;
  dst[(tid << 1) | 1] = v.y;
}
__device__ __forceinline__ void stage256(float* dst, const float* src, int tid) {
  if (tid < 128) {
    float2 v = cld2(src + (tid << 1));
    dst[tid << 1] = v.x;
    dst[(tid << 1) | 1] = v.y;
  }
}
__device__ __forceinline__ void stage128(float* dst, const float* src, int tid) {
  if (tid < 64) {
    float2 v = cld2(src + (tid << 1));
    dst[tid << 1] = v.x;
    dst[(tid << 1) | 1] = v.y;
  }
}

// 8-lane-group dots: matrix row from (cached) global, vector from LDS.
__device__ __forceinline__ float dot512L(const float* __restrict__ m,
                                         const float* v, int ls) {
  const float4* m4 = (const float4*)m;
  const float4* v4 = (const float4*)v;
  float s = 0.f;
#pragma unroll
  for (int it = 0; it < 16; ++it) {
    float4 a = m4[(it << 3) | ls];
    float4 b = v4[(it << 3) | ls];
    s = fmaf(a.x, b.x, s);
    s = fmaf(a.y, b.y, s);
    s = fmaf(a.z, b.z, s);
    s = fmaf(a.w, b.w, s);
  }
  return s;
}
__device__ __forceinline__ float dot128L(const float* __restrict__ m,
                                         const float* v, int ls) {
  const float4* m4 = (const float4*)m;
  const float4* v4 = (const float4*)v;
  float s = 0.f;
#pragma unroll
  for (int it = 0; it < 4; ++it) {
    float4 a = m4[(it << 3) | ls];
    float4 b = v4[(it << 3) | ls];
    s = fmaf(a.x, b.x, s);
    s = fmaf(a.y, b.y, s);
    s = fmaf(a.z, b.z, s);
    s = fmaf(a.w, b.w, s);
  }
  return s;
}

// ---------------------------------------------------------------------------
// Grid barrier, zero cache maintenance: vmcnt drain (sc1 stores ack at the
// coherence point), relaxed flag store, relaxed polls on padded slots.
// ---------------------------------------------------------------------------
__device__ __forceinline__ void grid_barrier(unsigned* __restrict__ arr,
                                             int bid, int tid, unsigned phase) {
  asm volatile("s_waitcnt vmcnt(0)" ::: "memory");
  __syncthreads();
  if (tid == 0)
    __hip_atomic_store(arr + (bid << 5), phase, __ATOMIC_RELAXED,
                       __HIP_MEMORY_SCOPE_AGENT);
  if (tid < NWG) {
    while (__hip_atomic_load(arr + (tid << 5), __ATOMIC_RELAXED,
                             __HIP_MEMORY_SCOPE_AGENT) < phase)
      __builtin_amdgcn_s_sleep(1);
  }
  __atomic_signal_fence(__ATOMIC_SEQ_CST);
  __syncthreads();
}

// ---------------------------------------------------------------------------
// Generic tiled fp32 GEMM: Z[M x N] = X[M x K] @ Y[K x N], row-major.
// ---------------------------------------------------------------------------
__global__ __launch_bounds__(256) void gemm_kernel(const float* __restrict__ X,
    const float* __restrict__ Y, float* __restrict__ Z, int M, int N, int Kd) {
  __shared__ float Xs[16][65];
  __shared__ float Ys[16][65];
  const int tx = threadIdx.x & 15;
  const int ty = threadIdx.x >> 4;
  const int mbase = blockIdx.y * 64;
  const int nbase = blockIdx.x * 64;
  float acc[4][4] = {};
  for (int k0 = 0; k0 < Kd; k0 += 16) {
#pragma unroll
    for (int r = 0; r < 4; ++r) {
      int idx = threadIdx.x + 256 * r;
      int mm = idx >> 4, kk = idx & 15;
      int gm = mbase + mm, gk = k0 + kk;
      Xs[kk][mm] = (gm < M && gk < Kd) ? X[(size_t)gm * Kd + gk] : 0.f;
      int nn = idx & 63, k2 = idx >> 6;
      int gn = nbase + nn, gk2 = k0 + k2;
      Ys[k2][nn] = (gk2 < Kd && gn < N) ? Y[(size_t)gk2 * N + gn] : 0.f;
    }
    __syncthreads();
#pragma unroll
    for (int kk = 0; kk < 16; ++kk) {
      float xv[4], yv[4];
#pragma unroll
      for (int a = 0; a < 4; ++a) xv[a] = Xs[kk][ty * 4 + a];
#pragma unroll
      for (int b = 0; b < 4; ++b) yv[b] = Ys[kk][tx * 4 + b];
#pragma unroll
      for (int a = 0; a < 4; ++a)
#pragma unroll
        for (int b = 0; b < 4; ++b) acc[a][b] += xv[a] * yv[b];
    }
    __syncthreads();
  }
#pragma unroll
  for (int a = 0; a < 4; ++a) {
    int gm = mbase + ty * 4 + a;
    if (gm < M) {
#pragma unroll
      for (int b = 0; b < 4; ++b) {
        int gn = nbase + tx * 4 + b;
        if (gn < N) Z[(size_t)gm * N + gn] = acc[a][b];
      }
    }
  }
}

// ---------------------------------------------------------------------------
// M2[c][i][q] = sum_j M_tensor[c][i][j][q] * s_m[j]
// ---------------------------------------------------------------------------
__global__ __launch_bounds__(256) void m2_kernel(const float* __restrict__ MT,
    const float* __restrict__ sm, float* __restrict__ M2g) {
  int idx = blockIdx.x * 256 + threadIdx.x;  // c*8192 + i*256 + q
  if (idx >= 128 * 32 * 256) return;
  int q = idx & 255;
  int ci = idx >> 8;
  const float* base = MT + (size_t)ci * 32 * 256 + q;
  float acc = 0.f;
#pragma unroll
  for (int j = 0; j < 32; ++j) acc += base[j * 256] * sm[j];
  M2g[idx] = acc;
}

// ---------------------------------------------------------------------------
// FIR bank: W[j][c][q] = sum_i M2[c][i][q] * Phi[i][j], j=0..63.
// ---------------------------------------------------------------------------
__global__ __launch_bounds__(256) void wfir_kernel(const float* __restrict__ M2g,
    const float* __restrict__ Phi, float* __restrict__ W) {
  int idx = blockIdx.x * 256 + threadIdx.x;  // j*32768 + c*256 + q
  if (idx >= 64 * 32768) return;
  int j = idx >> 15;
  int cq = idx & 32767;
  int c = cq >> 8;
  int q = cq & 255;
  float acc = 0.f;
#pragma unroll
  for (int i = 0; i < 32; ++i)
    acc = fmaf(Phi[(i << 6) | j], M2g[(size_t)(((c << 5) | i) << 8) | q], acc);
  W[idx] = acc;
}

// ---------------------------------------------------------------------------
__global__ void init_kernel(const float* __restrict__ x0, float* __restrict__ xh,
    float* __restrict__ dbuf, unsigned* __restrict__ arr) {
  int tid = blockIdx.x * 256 + threadIdx.x;
  if (tid < 512) {
    xh[tid] = x0[tid];
    dbuf[tid] = x0[tid];
    dbuf[512 + tid] = 0.f;
  }
  if (tid < NWG * 32) arr[tid] = 0u;
}

// ---------------------------------------------------------------------------
// Persistent main loop, one barrier per step. Roles:
//   WG  0..15 : x_t = A x_{t-1} + B u_{t-1}           (32 8-lane groups each)
//   WG 16..23 : y_nat_t = C d_t
//   WG 24..39 : d_{t+1} = A d_t + A33B u_{t-33}
//   WG 40..103: u_t[c0,c0+1] = -KCA x_{t-1} - KCB u_{t-1} + W0C d_t
//               + sum_{j=1..63} W[j][c] . y_nat_{t-j}   (ring in LDS)
// All cross-WG vectors staged once per WG into LDS via coherent 8B loads;
// matrices read with plain cached loads (L2-resident, never invalidated).
// ---------------------------------------------------------------------------
__global__ __launch_bounds__(TPB, 1) void main_kernel(
    const float* __restrict__ A, const float* __restrict__ B,
    const float* __restrict__ C, const float* __restrict__ x0,
    const float* __restrict__ Wfir, const float* __restrict__ W0C,
    const float* __restrict__ KC, const float* __restrict__ KCA,
    const float* __restrict__ KCB, const float* __restrict__ A33B,
    float* __restrict__ xh, float* __restrict__ uh, float* __restrict__ ynh,
    float* __restrict__ dbuf, unsigned* __restrict__ arr) {
  __shared__ float ring[64][256];  // y_nat history (u-WGs)
  __shared__ float xs[512];
  __shared__ float dsh[512];
  __shared__ float us[128];
  __shared__ float red[TPB];
  const int bid = blockIdx.x;
  const int tid = threadIdx.x;
  const int grp8 = tid >> 3;
  const int ls = tid & 7;

#pragma unroll 1
  for (int t = 0; t < 1024; ++t) {
    const float* xprev = xh + (size_t)(t > 0 ? t - 1 : 0) * 512;
    const float* uprev = uh + (size_t)(t > 0 ? t - 1 : 0) * 128;
    const float* dcur = dbuf + (t & 1) * 512;
    float* dnext = dbuf + ((t + 1) & 1) * 512;

    if (bid < 16) {
      // ---- x_t ----
      if (t > 0) {
        stage512(xs, xprev, tid);
        stage128(us, uprev, tid);
        __syncthreads();
        const int d = (bid << 5) | grp8;
        float acc = dot512L(A + (size_t)d * 512, xs, ls) +
                    dot128L(B + (size_t)d * 128, us, ls);
        acc += __shfl_down(acc, 4);
        acc += __shfl_down(acc, 2);
        acc += __shfl_down(acc, 1);
        if (ls == 0) cst(xh + (size_t)t * 512 + d, acc);
      }
    } else if (bid < 24) {
      // ---- y_nat_t = C d_t ----
      stage512(dsh, dcur, tid);
      __syncthreads();
      const int p = ((bid - 16) << 5) | grp8;
      float acc = dot512L(C + (size_t)p * 512, dsh, ls);
      acc += __shfl_down(acc, 4);
      acc += __shfl_down(acc, 2);
      acc += __shfl_down(acc, 1);
      if (ls == 0) cst(ynh + (size_t)t * 256 + p, acc);
    } else if (bid < 40) {
      // ---- d_{t+1} = A d_t + A33B u_{t-33} ----
      stage512(dsh, dcur, tid);
      if (t >= 33) stage128(us, uh + (size_t)(t - 33) * 128, tid);
      __syncthreads();
      const int d = ((bid - 24) << 5) | grp8;
      float acc = dot512L(A + (size_t)d * 512, dsh, ls);
      if (t >= 33) acc += dot128L(A33B + (size_t)d * 128, us, ls);
      acc += __shfl_down(acc, 4);
      acc += __shfl_down(acc, 2);
      acc += __shfl_down(acc, 1);
      if (ls == 0) cst(dnext + d, acc);
    } else {
      // ---- u_t ----
      stage512(xs, xprev, tid);
      stage512(dsh, dcur, tid);
      stage128(us, uprev, tid);
      if (t > 0) stage256(&ring[(t - 1) & 63][0], ynh + (size_t)(t - 1) * 256, tid);
      __syncthreads();

      const int c0 = (bid - 40) * 2;
      const int half = tid >> 7;
      const int k = tid & 127;
      const int c = c0 + half;
      float acc = 0.f;

      // FIR over y_nat history: j = 1 .. min(t,63)
      const int jmax = (t < 63) ? t : 63;
      const float* wbase = Wfir + (size_t)c * 256;
#pragma unroll 2
      for (int j = 1; j <= jmax; ++j) {
        const float* wr = wbase + (size_t)j * 32768;
        const float* rr = &ring[(t - j) & 63][0];
        acc = fmaf(wr[k], rr[k], acc);
        acc = fmaf(wr[k + 128], rr[k + 128], acc);
      }
      // W0C . d_t
      const float* w0cr = W0C + (size_t)c * 512;
#pragma unroll
      for (int kk = 0; kk < 4; ++kk)
        acc = fmaf(w0cr[k + kk * 128], dsh[k + kk * 128], acc);
      if (t == 0) {
        const float* kcr = KC + (size_t)c * 512;
#pragma unroll
        for (int kk = 0; kk < 4; ++kk) acc -= kcr[k + kk * 128] * xs[k + kk * 128];
      } else {
        const float* kcar = KCA + (size_t)c * 512;
#pragma unroll
        for (int kk = 0; kk < 4; ++kk) acc -= kcar[k + kk * 128] * xs[k + kk * 128];
        acc -= KCB[(size_t)c * 128 + k] * us[k];
      }
      red[tid] = acc;
      __syncthreads();
      if (k < 64) red[tid] += red[tid + 64];
      __syncthreads();
      if (k < 64) {
        float v = red[(half << 7) | k];
        v += __shfl_down(v, 32);
        v += __shfl_down(v, 16);
        v += __shfl_down(v, 8);
        v += __shfl_down(v, 4);
        v += __shfl_down(v, 2);
        v += __shfl_down(v, 1);
        if (k == 0) cst(uh + (size_t)t * 128 + c, v);
      }
    }

    grid_barrier(arr, bid, tid, (unsigned)(t + 1));
  }
}

// ---------------------------------------------------------------------------
// Epilogue (parallel over t): y_obs_t = CA x_{t-1} + CB u_{t-1} (t=0: C x0),
// cost_t = y^T Q y + u^T R u. Coherent reads of xh/uh (sc1 stores bypass L2).
// ---------------------------------------------------------------------------
__global__ __launch_bounds__(256) void cost_kernel(const float* __restrict__ CA,
    const float* __restrict__ CB, const float* __restrict__ C,
    const float* __restrict__ Q, const float* __restrict__ R,
    const float* __restrict__ x0, const float* __restrict__ xh,
    const float* __restrict__ uh, float* __restrict__ out) {
  __shared__ float xs[512];
  __shared__ float us[128];
  __shared__ float up[128];
  __shared__ float yo[256];
  __shared__ float red[256];
  const int t = blockIdx.x;
  const int tid = threadIdx.x;
  if (t > 0) {
    float2 v = cld2(xh + (size_t)(t - 1) * 512 + tid * 2);
    xs[tid * 2] = v.x;
    xs[tid * 2 + 1] = v.y;
    if (tid >= 128) up[tid - 128] = cld(uh + (size_t)(t - 1) * 128 + (tid - 128));
  } else {
    xs[tid] = x0[tid];
    xs[tid + 256] = x0[tid + 256];
  }
  if (tid < 128) us[tid] = cld(uh + (size_t)t * 128 + tid);
  __syncthreads();

  float acc = 0.f;
  if (t == 0) {
    const float* Cr = C + (size_t)tid * 512;
    for (int k = 0; k < 512; ++k) acc = fmaf(Cr[k], xs[k], acc);
  } else {
    const float* CAr = CA + (size_t)tid * 512;
    for (int k = 0; k < 512; ++k) acc = fmaf(CAr[k], xs[k], acc);
    const float* CBr = CB + (size_t)tid * 128;
    for (int k = 0; k < 128; ++k) acc = fmaf(CBr[k], up[k], acc);
  }
  yo[tid] = acc;
  __syncthreads();

  const float* Qr = Q + (size_t)tid * 256;
  float qy = 0.f;
  for (int k = 0; k < 256; ++k) qy = fmaf(Qr[k], yo[k], qy);
  float cc = qy * yo[tid];
  if (tid < 128) {
    const float* Rr = R + (size_t)tid * 128;
    float ru = 0.f;
    for (int k = 0; k < 128; ++k) ru = fmaf(Rr[k], us[k], ru);
    cc += ru * us[tid];
  }
  red[tid] = cc;
  __syncthreads();
  if (tid < 128) red[tid] += red[tid + 128];
  __syncthreads();
  if (tid < 64) {
    float v = red[tid] + red[tid + 64];
    v += __shfl_down(v, 32);
    v += __shfl_down(v, 16);
    v += __shfl_down(v, 8);
    v += __shfl_down(v, 4);
    v += __shfl_down(v, 2);
    v += __shfl_down(v, 1);
    if (tid == 0) out[t] = v;
  }
}

// ---------------------------------------------------------------------------
extern "C" void kernel_launch(void* const* d_in, const int* in_sizes, int n_in,
                              void* d_out, int out_size, void* d_ws, size_t ws_size,
                              hipStream_t stream) {
  (void)in_sizes; (void)n_in; (void)out_size; (void)ws_size;
  const float* A = (const float*)d_in[0];
  const float* B = (const float*)d_in[1];
  const float* C = (const float*)d_in[2];
  const float* Q = (const float*)d_in[3];
  const float* R = (const float*)d_in[4];
  const float* K = (const float*)d_in[5];
  const float* MT = (const float*)d_in[6];
  const float* Phi = (const float*)d_in[7];
  const float* sm = (const float*)d_in[8];
  const float* x0 = (const float*)d_in[9];

  float* ws = (float*)d_ws;
  float* M2g = ws;                 // 1048576 (reused for A2..A16 after wfir)
  float* Wfir = M2g + 1048576;     // 2097152 (64*128*256)
  float* W0C = Wfir + 2097152;     // 65536
  float* KC = W0C + 65536;         // 65536
  float* KCA = KC + 65536;         // 65536
  float* KCB = KCA + 65536;        // 16384
  float* CAm = KCB + 16384;        // 131072
  float* CBm = CAm + 131072;       // 32768
  float* ABm = CBm + 32768;        // 65536
  float* A32 = ABm + 65536;        // 262144
  float* A33B = A32 + 262144;      // 65536
  float* xh = A33B + 65536;        // 1024*512
  float* uh = xh + 524288;         // 1024*128
  float* ynh = uh + 131072;        // 1024*256
  float* dbuf = ynh + 262144;      // 2*512
  unsigned* arr = (unsigned*)(dbuf + 1024);  // NWG*32 u32
  // A-power chain aliases M2g (dead after wfir_kernel):
  float* A2 = M2g;
  float* A4 = M2g + 262144;
  float* A8 = M2g + 524288;
  float* A16 = M2g + 786432;

  auto gemm = [&](const float* X, const float* Y, float* Z, int M, int N, int Kd) {
    dim3 g((N + 63) / 64, (M + 63) / 64);
    gemm_kernel<<<g, dim3(256), 0, stream>>>(X, Y, Z, M, N, Kd);
  };

  init_kernel<<<dim3(64), dim3(256), 0, stream>>>(x0, xh, dbuf, arr);
  m2_kernel<<<dim3(4096), dim3(256), 0, stream>>>(MT, sm, M2g);
  wfir_kernel<<<dim3(8192), dim3(256), 0, stream>>>(M2g, Phi, Wfir);

  gemm(Wfir, C, W0C, 128, 512, 256);  // W[0] slice is [c][q] row-major
  gemm(K, C, KC, 128, 512, 256);
  gemm(KC, A, KCA, 128, 512, 512);
  gemm(KC, B, KCB, 128, 128, 512);
  gemm(C, A, CAm, 256, 512, 512);
  gemm(C, B, CBm, 256, 128, 512);
  gemm(A, B, ABm, 512, 128, 512);
  gemm(A, A, A2, 512, 512, 512);      // overwrites M2g (dead)
  gemm(A2, A2, A4, 512, 512, 512);
  gemm(A4, A4, A8, 512, 512, 512);
  gemm(A8, A8, A16, 512, 512, 512);
  gemm(A16, A16, A32, 512, 512, 512);
  gemm(A32, ABm, A33B, 512, 128, 512);

  main_kernel<<<dim3(NWG), dim3(TPB), 0, stream>>>(
      A, B, C, x0, Wfir, W0C, KC, KCA, KCB, A33B, xh, uh, ynh, dbuf, arr);

  cost_kernel<<<dim3(1024), dim3(256), 0, stream>>>(CAm, CBm, C, Q, R, x0, xh, uh,
                                                    (float*)d_out);
}

// Round 5
// 4765.111 us; speedup vs baseline: 6.5721x; 1.6668x over previous
//
#include <hip/hip_runtime.h>

#define TPB 256
#define NWG 216

// ---------------------------------------------------------------------------
// Coherent (agent-scope, MALL-served) helpers: sc1 loads/stores, no fences.
// ---------------------------------------------------------------------------
__device__ __forceinline__ void cst(float* p, float v) {
  __hip_atomic_store(p, v, __ATOMIC_RELAXED, __HIP_MEMORY_SCOPE_AGENT);
}
__device__ __forceinline__ void cstu(unsigned* p, unsigned v) {
  __hip_atomic_store(p, v, __ATOMIC_RELAXED, __HIP_MEMORY_SCOPE_AGENT);
}
__device__ __forceinline__ float cld(const float* p) {
  return __hip_atomic_load(p, __ATOMIC_RELAXED, __HIP_MEMORY_SCOPE_AGENT);
}
__device__ __forceinline__ float2 cld2(const float* p) {
  unsigned long long u = __hip_atomic_load(
      reinterpret_cast<const unsigned long long*>(p), __ATOMIC_RELAXED,
      __HIP_MEMORY_SCOPE_AGENT);
  float2 v;
  __builtin_memcpy(&v, &u, 8);
  return v;
}

// ---------------------------------------------------------------------------
// Grid barrier: vmcnt drain (sc1 stores+atomics ack at coherence point),
// relaxed flag store, relaxed polls on padded slots. No cache maintenance.
// ---------------------------------------------------------------------------
__device__ __forceinline__ void grid_barrier(unsigned* __restrict__ arr,
                                             int bid, int tid, unsigned phase) {
  asm volatile("s_waitcnt vmcnt(0)" ::: "memory");
  __syncthreads();
  if (tid == 0)
    __hip_atomic_store(arr + (bid << 5), phase, __ATOMIC_RELAXED,
                       __HIP_MEMORY_SCOPE_AGENT);
  if (tid < NWG) {
    while (__hip_atomic_load(arr + (tid << 5), __ATOMIC_RELAXED,
                             __HIP_MEMORY_SCOPE_AGENT) < phase)
      __builtin_amdgcn_s_sleep(1);
  }
  __atomic_signal_fence(__ATOMIC_SEQ_CST);
  __syncthreads();
}

// ---------------------------------------------------------------------------
// Generic tiled fp32 GEMM tile body: Z[M x N] = X[M x K] @ Y[K x N].
// ---------------------------------------------------------------------------
__device__ void gemm_tile(const float* __restrict__ X, const float* __restrict__ Y,
                          float* __restrict__ Z, int M, int N, int Kd,
                          int mtile, int ntile) {
  __shared__ float Xs[16][65];
  __shared__ float Ys[16][65];
  const int tx = threadIdx.x & 15;
  const int ty = threadIdx.x >> 4;
  const int mbase = mtile * 64;
  const int nbase = ntile * 64;
  float acc[4][4] = {};
  for (int k0 = 0; k0 < Kd; k0 += 16) {
#pragma unroll
    for (int r = 0; r < 4; ++r) {
      int idx = threadIdx.x + 256 * r;
      int mm = idx >> 4, kk = idx & 15;
      int gm = mbase + mm, gk = k0 + kk;
      Xs[kk][mm] = (gm < M && gk < Kd) ? X[(size_t)gm * Kd + gk] : 0.f;
      int nn = idx & 63, k2 = idx >> 6;
      int gn = nbase + nn, gk2 = k0 + k2;
      Ys[k2][nn] = (gk2 < Kd && gn < N) ? Y[(size_t)gk2 * N + gn] : 0.f;
    }
    __syncthreads();
#pragma unroll
    for (int kk = 0; kk < 16; ++kk) {
      float xv[4], yv[4];
#pragma unroll
      for (int a = 0; a < 4; ++a) xv[a] = Xs[kk][ty * 4 + a];
#pragma unroll
      for (int b = 0; b < 4; ++b) yv[b] = Ys[kk][tx * 4 + b];
#pragma unroll
      for (int a = 0; a < 4; ++a)
#pragma unroll
        for (int b = 0; b < 4; ++b) acc[a][b] += xv[a] * yv[b];
    }
    __syncthreads();
  }
#pragma unroll
  for (int a = 0; a < 4; ++a) {
    int gm = mbase + ty * 4 + a;
    if (gm < M) {
#pragma unroll
      for (int b = 0; b < 4; ++b) {
        int gn = nbase + tx * 4 + b;
        if (gn < N) Z[(size_t)gm * N + gn] = acc[a][b];
      }
    }
  }
}

__global__ __launch_bounds__(256) void gemm_kernel(const float* __restrict__ X,
    const float* __restrict__ Y, float* __restrict__ Z, int M, int N, int Kd) {
  gemm_tile(X, Y, Z, M, N, Kd, blockIdx.y, blockIdx.x);
}

// ---------------------------------------------------------------------------
// Fused chain step s (s=2..16): 7 products, all K=512.
//   P[s]=P[s-1]@Acl; CAp[s]=CAp[s-1]@A; W0CA[s]=W0CA[s-1]@A;
//   Rn[s]=Acl@Rn[s-1]; AB33[s]=A@AB33[s-1];
//   CAB33[s]=CAp[s-1]@AB33[1]; W0CAB33[s]=W0CA[s-1]@AB33[1]
// slot convention: Pp[k]=P[k+1], CApp[k]=CAp[k+1], W0CAp[k]=W0CA[k+1],
// Rnp[k]=Rn[k+1]; AB33p/CAB33p/W0CAB33p indexed directly by power.
// ---------------------------------------------------------------------------
__global__ __launch_bounds__(256) void chainstep_kernel(int s,
    const float* __restrict__ A, const float* __restrict__ Acl,
    float* Pp, float* CApp, float* W0CAp, float* Rnp, float* AB33p,
    float* CAB33p, float* W0CAB33p) {
  int b = blockIdx.x;
  const float *X, *Y;
  float* Z;
  int M, N, mt, nt;
  if (b < 64) { mt = b >> 3; nt = b & 7; X = Pp + (size_t)(s - 2) * 262144; Y = Acl; Z = Pp + (size_t)(s - 1) * 262144; M = 512; N = 512; }
  else if (b < 96) { int i = b - 64; mt = i >> 3; nt = i & 7; X = CApp + (size_t)(s - 2) * 131072; Y = A; Z = CApp + (size_t)(s - 1) * 131072; M = 256; N = 512; }
  else if (b < 112) { int i = b - 96; mt = i >> 3; nt = i & 7; X = W0CAp + (size_t)(s - 2) * 65536; Y = A; Z = W0CAp + (size_t)(s - 1) * 65536; M = 128; N = 512; }
  else if (b < 128) { int i = b - 112; mt = i >> 1; nt = i & 1; X = Acl; Y = Rnp + (size_t)(s - 2) * 65536; Z = Rnp + (size_t)(s - 1) * 65536; M = 512; N = 128; }
  else if (b < 144) { int i = b - 128; mt = i >> 1; nt = i & 1; X = A; Y = AB33p + (size_t)(s - 1) * 65536; Z = AB33p + (size_t)s * 65536; M = 512; N = 128; }
  else if (b < 152) { int i = b - 144; mt = i >> 1; nt = i & 1; X = CApp + (size_t)(s - 2) * 131072; Y = AB33p + 65536; Z = CAB33p + (size_t)s * 32768; M = 256; N = 128; }
  else { int i = b - 152; mt = i >> 1; nt = i & 1; X = W0CAp + (size_t)(s - 2) * 65536; Y = AB33p + 65536; Z = W0CAB33p + (size_t)s * 16384; M = 128; N = 128; }
  gemm_tile(X, Y, Z, M, N, 512, mt, nt);
}

// ---------------------------------------------------------------------------
__global__ __launch_bounds__(256) void m2_kernel(const float* __restrict__ MT,
    const float* __restrict__ sm, float* __restrict__ M2g) {
  int idx = blockIdx.x * 256 + threadIdx.x;
  if (idx >= 128 * 32 * 256) return;
  int q = idx & 255;
  int ci = idx >> 8;
  const float* base = MT + (size_t)ci * 32 * 256 + q;
  float acc = 0.f;
#pragma unroll
  for (int j = 0; j < 32; ++j) acc += base[j * 256] * sm[j];
  M2g[idx] = acc;
}

__global__ __launch_bounds__(256) void wfir_kernel(const float* __restrict__ M2g,
    const float* __restrict__ Phi, float* __restrict__ W) {
  int idx = blockIdx.x * 256 + threadIdx.x;  // j*32768 + c*256 + q
  if (idx >= 64 * 32768) return;
  int j = idx >> 15;
  int cq = idx & 32767;
  int c = cq >> 8;
  int q = cq & 255;
  float acc = 0.f;
#pragma unroll
  for (int i = 0; i < 32; ++i)
    acc = fmaf(Phi[(i << 6) | j], M2g[(size_t)(((c << 5) | i) << 8) | q], acc);
  W[idx] = acc;
}

// Acl = A - BKC; also copy into P[1] slot.
__global__ __launch_bounds__(256) void axpy_acl(const float* __restrict__ A,
    const float* __restrict__ BKC, float* __restrict__ Acl, float* __restrict__ P1) {
  int i = blockIdx.x * 256 + threadIdx.x;
  if (i < 262144) {
    float v = A[i] - BKC[i];
    Acl[i] = v;
    P1[i] = v;
  }
}

// ---------------------------------------------------------------------------
// init: coherent-zero xh, eh, ynh, uh pad, arr; dbnd[0] = x0.
// (sc1 stores so no stale dirty L2 lines can later clobber MALL data.)
// ---------------------------------------------------------------------------
__global__ void init_kernel(const float* __restrict__ x0, float* __restrict__ xh,
    float* __restrict__ eh, float* __restrict__ ynh, float* __restrict__ uh0,
    float* __restrict__ dbnd, unsigned* __restrict__ arr) {
  int i = blockIdx.x * 256 + threadIdx.x;
  int stride = gridDim.x * 256;
  for (int k = i; k < 524288; k += stride) cst(xh + k, 0.f);
  for (int k = i; k < 139392; k += stride) cst(eh + k, 0.f);
  for (int k = i; k < 262144; k += stride) cst(ynh + k, 0.f);
  for (int k = i; k < 8192; k += stride) cst(uh0 + k, 0.f);  // 64 pad rows
  for (int k = i; k < NWG * 32; k += stride) cstu(arr + k, 0u);
  if (i < 512) cst(dbnd + i, x0[i]);
}

// ---------------------------------------------------------------------------
// Persistent main loop. 65 phases x 2 barriers. Phase ph, T=16*ph, Tp=T-16.
// sub-A roles (block p=ph, and x-lift of block p-1):
//   WG   0.. 63 Yd : y_nat[T+s] += CAp[s] d_T           (s=WG>>2, 64-row qtr)
//   WG  64.. 79 Yu : y_nat[T+s] += sum_m CAB33[m] u_{T+s-m-34}
//   WG  80.. 95 Wd : e[T+s]     += W0CA[s] d_T
//   WG  96..103 Wu : e[T+s]     += sum_m W0CAB33[m] u_{T+s-m-34}
//   WG 104..119 Dt : dbnd[ph+1] = A^16 d_T + sum_m AB33[m] u_{T+15-m-33}
//   WG 120..183 Xp : x[Tp+s]    += P[s+1] x_{Tp-1}      (ph>=1; ph==1: P[s] x0)
//   WG 184..215 Xr : x[Tp+s]    += sum_i Rn[i] e_{Tp+s-1-i}   (Rn[0]=B)
// sub-B roles:
//   WG   0..127 SC : e[T+s+j]   += W[j]·y_nat[T+s]  (j=1..63; c=WG; W in LDS)
//   WG 128..159 U  : u[Tp+s]    = -KC x_{Tp+s} + e_{Tp+s}
// ---------------------------------------------------------------------------
__global__ __launch_bounds__(TPB, 1) void main_kernel(
    const float* __restrict__ B, const float* __restrict__ C,
    const float* __restrict__ x0, const float* __restrict__ Wfir,
    const float* __restrict__ KC, const float* __restrict__ W0C,
    const float* __restrict__ Pp, const float* __restrict__ CApp,
    const float* __restrict__ W0CAp, const float* __restrict__ Rnp,
    const float* __restrict__ AB33p, const float* __restrict__ CAB33p,
    const float* __restrict__ W0CAB33p, const float* __restrict__ A16k,
    float* __restrict__ xh, float* __restrict__ uh0, float* __restrict__ eh,
    float* __restrict__ ynh, float* __restrict__ dbnd,
    unsigned* __restrict__ arr) {
  __shared__ float smA[64 * 256];   // SC: Wfir c-slice [j][q]
  __shared__ float smY[16 * 256];   // SC: y-block
  __shared__ float smV[512];        // staged d / x vector
  __shared__ float smW[16 * 128];   // staged u/e window
  __shared__ float redsc[4][16];
  const int bid = blockIdx.x;
  const int tid = threadIdx.x;

  // Load Wfir c-slice into LDS once (WGs 0..127; c = bid).
  if (bid < 128) {
    for (int i = tid; i < 16384; i += TPB) {
      int j = i >> 8;
      smA[i] = (j >= 1) ? Wfir[(size_t)j * 32768 + bid * 256 + (i & 255)] : 0.f;
    }
  }
  __syncthreads();

  unsigned bcnt = 0;
#pragma unroll 1
  for (int ph = 0; ph <= 64; ++ph) {
    const int T = ph * 16;
    const int Tp = T - 16;

    // ================= sub-A =================
    if (bid < 64) {  // ---- Yd ----
      if (ph < 64) {
        const int s = bid >> 2;
        const int pq = (bid & 3) * 64;
        {
          float2 v = cld2(dbnd + (size_t)ph * 512 + 2 * tid);
          smV[2 * tid] = v.x;
          smV[2 * tid + 1] = v.y;
        }
        __syncthreads();
        const float* Mrow = (s == 0) ? C : (CApp + (size_t)(s - 1) * 131072);
        const int row = pq + (tid >> 2);
        const int ks = (tid & 3) * 128;
        const float4* m4 = (const float4*)(Mrow + (size_t)row * 512 + ks);
        const float4* v4 = (const float4*)(smV + ks);
        float a = 0.f;
#pragma unroll
        for (int it = 0; it < 32; ++it) {
          float4 mm = m4[it], vv = v4[it];
          a += mm.x * vv.x + mm.y * vv.y + mm.z * vv.z + mm.w * vv.w;
        }
        a += __shfl_down(a, 2);
        a += __shfl_down(a, 1);
        if ((tid & 3) == 0) atomicAdd(&ynh[(size_t)(T + s) * 256 + row], a);
        __syncthreads();
      }
    } else if (bid < 80) {  // ---- Yu ----
      if (ph < 64) {
        const int g = bid - 64;
        for (int i2 = tid; i2 < 1024; i2 += TPB) {
          float2 v = cld2(uh0 + (size_t)(64 + T - 33) * 128 + 2 * i2);
          smW[2 * i2] = v.x;
          smW[2 * i2 + 1] = v.y;
        }
        __syncthreads();
        const int row = g * 16 + (tid >> 4);
        const int l16 = tid & 15;
        const int qs = l16 * 8;
        float acc[16];
#pragma unroll
        for (int s = 0; s < 16; ++s) acc[s] = 0.f;
#pragma unroll
        for (int m = 0; m < 15; ++m) {
          const float4* cr = (const float4*)(CAB33p + (size_t)m * 32768 + (size_t)row * 128 + qs);
          float4 c0 = cr[0], c1 = cr[1];
#pragma unroll
          for (int s = 0; s < 16; ++s) {
            if (s > m) {
              const float* u = smW + (s - m - 1) * 128 + qs;
              acc[s] += c0.x * u[0] + c0.y * u[1] + c0.z * u[2] + c0.w * u[3] +
                        c1.x * u[4] + c1.y * u[5] + c1.z * u[6] + c1.w * u[7];
            }
          }
        }
#pragma unroll
        for (int s = 0; s < 16; ++s) {
          float v = acc[s];
          v += __shfl_xor(v, 8);
          v += __shfl_xor(v, 4);
          v += __shfl_xor(v, 2);
          v += __shfl_xor(v, 1);
          if (l16 == 0 && s >= 1) atomicAdd(&ynh[(size_t)(T + s) * 256 + row], v);
        }
        __syncthreads();
      }
    } else if (bid < 96) {  // ---- Wd ----
      if (ph < 64) {
        const int s = bid - 80;
        {
          float2 v = cld2(dbnd + (size_t)ph * 512 + 2 * tid);
          smV[2 * tid] = v.x;
          smV[2 * tid + 1] = v.y;
        }
        __syncthreads();
        const float* Mrow = (s == 0) ? W0C : (W0CAp + (size_t)(s - 1) * 65536);
        const int row = tid >> 1;
        const int ks = (tid & 1) * 256;
        const float4* m4 = (const float4*)(Mrow + (size_t)row * 512 + ks);
        const float4* v4 = (const float4*)(smV + ks);
        float a = 0.f;
#pragma unroll
        for (int it = 0; it < 64; ++it) {
          float4 mm = m4[it], vv = v4[it];
          a += mm.x * vv.x + mm.y * vv.y + mm.z * vv.z + mm.w * vv.w;
        }
        a += __shfl_down(a, 1);
        if ((tid & 1) == 0) atomicAdd(&eh[(size_t)(T + s) * 128 + row], a);
        __syncthreads();
      }
    } else if (bid < 104) {  // ---- Wu ----
      if (ph < 64) {
        const int g = bid - 96;
        for (int i2 = tid; i2 < 1024; i2 += TPB) {
          float2 v = cld2(uh0 + (size_t)(64 + T - 33) * 128 + 2 * i2);
          smW[2 * i2] = v.x;
          smW[2 * i2 + 1] = v.y;
        }
        __syncthreads();
        const int row = g * 16 + (tid >> 4);
        const int l16 = tid & 15;
        const int qs = l16 * 8;
        float acc[16];
#pragma unroll
        for (int s = 0; s < 16; ++s) acc[s] = 0.f;
#pragma unroll
        for (int m = 0; m < 15; ++m) {
          const float4* cr = (const float4*)(W0CAB33p + (size_t)m * 16384 + (size_t)row * 128 + qs);
          float4 c0 = cr[0], c1 = cr[1];
#pragma unroll
          for (int s = 0; s < 16; ++s) {
            if (s > m) {
              const float* u = smW + (s - m - 1) * 128 + qs;
              acc[s] += c0.x * u[0] + c0.y * u[1] + c0.z * u[2] + c0.w * u[3] +
                        c1.x * u[4] + c1.y * u[5] + c1.z * u[6] + c1.w * u[7];
            }
          }
        }
#pragma unroll
        for (int s = 0; s < 16; ++s) {
          float v = acc[s];
          v += __shfl_xor(v, 8);
          v += __shfl_xor(v, 4);
          v += __shfl_xor(v, 2);
          v += __shfl_xor(v, 1);
          if (l16 == 0 && s >= 1) atomicAdd(&eh[(size_t)(T + s) * 128 + row], v);
        }
        __syncthreads();
      }
    } else if (bid < 120) {  // ---- Dt ----
      if (ph < 64) {
        const int g = bid - 104;
        {
          float2 v = cld2(dbnd + (size_t)ph * 512 + 2 * tid);
          smV[2 * tid] = v.x;
          smV[2 * tid + 1] = v.y;
        }
        for (int i2 = tid; i2 < 1024; i2 += TPB) {
          float2 v = cld2(uh0 + (size_t)(64 + T - 33) * 128 + 2 * i2);
          smW[2 * i2] = v.x;
          smW[2 * i2 + 1] = v.y;
        }
        __syncthreads();
        const int row = g * 32 + (tid >> 3);
        const int l8 = tid & 7;
        float a = 0.f;
        {
          const float4* m4 = (const float4*)(A16k + (size_t)row * 512 + l8 * 64);
          const float4* v4 = (const float4*)(smV + l8 * 64);
#pragma unroll
          for (int it = 0; it < 16; ++it) {
            float4 mm = m4[it], vv = v4[it];
            a += mm.x * vv.x + mm.y * vv.y + mm.z * vv.z + mm.w * vv.w;
          }
        }
#pragma unroll
        for (int m = 0; m < 16; ++m) {
          const float4* m4 = (const float4*)(AB33p + (size_t)m * 65536 + (size_t)row * 128 + l8 * 16);
          const float4* v4 = (const float4*)(smW + (15 - m) * 128 + l8 * 16);
#pragma unroll
          for (int it = 0; it < 4; ++it) {
            float4 mm = m4[it], vv = v4[it];
            a += mm.x * vv.x + mm.y * vv.y + mm.z * vv.z + mm.w * vv.w;
          }
        }
        a += __shfl_down(a, 4);
        a += __shfl_down(a, 2);
        a += __shfl_down(a, 1);
        if (l8 == 0) cst(&dbnd[(size_t)(ph + 1) * 512 + row], a);
        __syncthreads();
      }
    } else if (bid < 184) {  // ---- Xp ----
      if (ph >= 1) {
        const int w = bid - 120;
        const int s = w >> 2;
        const int quarter = (w & 3) * 128;
        {
          const float* src = (ph == 1) ? x0 : (xh + (size_t)(Tp - 1) * 512);
          float2 v = cld2(src + 2 * tid);
          smV[2 * tid] = v.x;
          smV[2 * tid + 1] = v.y;
        }
        __syncthreads();
        const int pslot = (ph == 1) ? s : (s + 1);
        const int row = quarter + (tid >> 1);
        if (pslot == 0) {
          if ((tid & 1) == 0) atomicAdd(&xh[(size_t)(Tp + s) * 512 + row], smV[row]);
        } else {
          const float* Mrow = Pp + (size_t)(pslot - 1) * 262144;
          const int ks = (tid & 1) * 256;
          const float4* m4 = (const float4*)(Mrow + (size_t)row * 512 + ks);
          const float4* v4 = (const float4*)(smV + ks);
          float a = 0.f;
#pragma unroll
          for (int it = 0; it < 64; ++it) {
            float4 mm = m4[it], vv = v4[it];
            a += mm.x * vv.x + mm.y * vv.y + mm.z * vv.z + mm.w * vv.w;
          }
          a += __shfl_down(a, 1);
          if ((tid & 1) == 0) atomicAdd(&xh[(size_t)(Tp + s) * 512 + row], a);
        }
        __syncthreads();
      }
    } else {  // ---- Xr (bid 184..215) ----
      if (ph >= 1) {
        const int g = bid - 184;
        for (int i2 = tid; i2 < 1024; i2 += TPB) {
          int idx = 2 * i2;
          int r = idx >> 7;
          float2 v;
          if (ph == 1 && r == 0) {
            v.x = 0.f;
            v.y = 0.f;
          } else {
            v = cld2(eh + (size_t)(Tp - 1 + r) * 128 + (idx & 127));
          }
          smW[idx] = v.x;
          smW[idx + 1] = v.y;
        }
        __syncthreads();
        const int row = g * 16 + (tid >> 4);
        const int l16 = tid & 15;
        const int qs = l16 * 8;
        float acc[16];
#pragma unroll
        for (int s = 0; s < 16; ++s) acc[s] = 0.f;
#pragma unroll
        for (int i = 0; i < 16; ++i) {
          const float* Rrow = (i == 0) ? (B + (size_t)row * 128 + qs)
                                       : (Rnp + (size_t)(i - 1) * 65536 + (size_t)row * 128 + qs);
          const float4* cr = (const float4*)Rrow;
          float4 c0 = cr[0], c1 = cr[1];
#pragma unroll
          for (int s = 0; s < 16; ++s) {
            if (s >= i) {
              const float* e = smW + (s - i) * 128 + qs;
              acc[s] += c0.x * e[0] + c0.y * e[1] + c0.z * e[2] + c0.w * e[3] +
                        c1.x * e[4] + c1.y * e[5] + c1.z * e[6] + c1.w * e[7];
            }
          }
        }
#pragma unroll
        for (int s = 0; s < 16; ++s) {
          float v = acc[s];
          v += __shfl_xor(v, 8);
          v += __shfl_xor(v, 4);
          v += __shfl_xor(v, 2);
          v += __shfl_xor(v, 1);
          if (l16 == 0) atomicAdd(&xh[(size_t)(Tp + s) * 512 + row], v);
        }
        __syncthreads();
      }
    }

    grid_barrier(arr, bid, tid, ++bcnt);

    // ================= sub-B =================
    if (bid < 128) {  // ---- SC ----
      if (ph < 64) {
        const int c = bid;
        for (int i2 = tid; i2 < 2048; i2 += TPB) {
          float2 v = cld2(ynh + (size_t)T * 256 + 2 * i2);
          smY[2 * i2] = v.x;
          smY[2 * i2 + 1] = v.y;
        }
        __syncthreads();
        const int q = tid;
        float yreg[16];
#pragma unroll
        for (int s = 0; s < 16; ++s) yreg[s] = smY[s * 256 + q];
        const int wv = tid >> 6;
        const int lane = tid & 63;
#pragma unroll
        for (int kt = 0; kt < 5; ++kt) {
          const int r0 = 1 + 16 * kt;
          float wreg[31];
#pragma unroll
          for (int i = 0; i < 31; ++i) {
            const int j = r0 - 15 + i;
            wreg[i] = (j >= 1 && j <= 63) ? smA[j * 256 + q] : 0.f;
          }
          float acc[16];
#pragma unroll
          for (int a = 0; a < 16; ++a) acc[a] = 0.f;
#pragma unroll
          for (int a = 0; a < 16; ++a)
#pragma unroll
            for (int s = 0; s < 16; ++s) acc[a] += wreg[a + 15 - s] * yreg[s];
#pragma unroll
          for (int a = 0; a < 16; ++a) {
            float v = acc[a];
            v += __shfl_xor(v, 32);
            v += __shfl_xor(v, 16);
            v += __shfl_xor(v, 8);
            v += __shfl_xor(v, 4);
            v += __shfl_xor(v, 2);
            v += __shfl_xor(v, 1);
            if (lane == 0) redsc[wv][a] = v;
          }
          __syncthreads();
          if (tid < 16) {
            float sum = redsc[0][tid] + redsc[1][tid] + redsc[2][tid] + redsc[3][tid];
            atomicAdd(&eh[(size_t)(T + r0 + tid) * 128 + c], sum);
          }
          __syncthreads();
        }
      }
    } else if (bid < 160) {  // ---- U ----
      if (ph >= 1) {
        const int g = bid - 128;
        const int s = g >> 1;
        const int ch = (g & 1) * 64;
        const int t = Tp + s;
        {
          float2 v = cld2(xh + (size_t)t * 512 + 2 * tid);
          smV[2 * tid] = v.x;
          smV[2 * tid + 1] = v.y;
        }
        __syncthreads();
        const int row = ch + (tid >> 2);
        const int ks = (tid & 3) * 128;
        const float4* m4 = (const float4*)(KC + (size_t)row * 512 + ks);
        const float4* v4 = (const float4*)(smV + ks);
        float a = 0.f;
#pragma unroll
        for (int it = 0; it < 32; ++it) {
          float4 mm = m4[it], vv = v4[it];
          a += mm.x * vv.x + mm.y * vv.y + mm.z * vv.z + mm.w * vv.w;
        }
        a += __shfl_down(a, 2);
        a += __shfl_down(a, 1);
        if ((tid & 3) == 0) {
          float u = cld(&eh[(size_t)t * 128 + row]) - a;
          cst(&uh0[(size_t)(64 + t) * 128 + row], u);
        }
        __syncthreads();
      }
    }

    grid_barrier(arr, bid, tid, ++bcnt);
  }
}

// ---------------------------------------------------------------------------
// Epilogue: y_obs_t = C x_t; cost_t = y'Q y + u'R u.  (one WG per t)
// ---------------------------------------------------------------------------
__global__ __launch_bounds__(256) void cost_kernel(const float* __restrict__ C,
    const float* __restrict__ Q, const float* __restrict__ R,
    const float* __restrict__ xh, const float* __restrict__ uh0,
    float* __restrict__ out) {
  __shared__ float xs[512];
  __shared__ float ys[256];
  __shared__ float us[128];
  __shared__ float redw[4];
  const int t = blockIdx.x;
  const int tid = threadIdx.x;
  {
    float2 v = cld2(xh + (size_t)t * 512 + 2 * tid);
    xs[2 * tid] = v.x;
    xs[2 * tid + 1] = v.y;
  }
  if (tid < 64) {
    float2 v = cld2(uh0 + (size_t)(64 + t) * 128 + 2 * tid);
    us[2 * tid] = v.x;
    us[2 * tid + 1] = v.y;
  }
  __syncthreads();
  {
    const float4* m4 = (const float4*)(C + (size_t)tid * 512);
    const float4* v4 = (const float4*)xs;
    float a = 0.f;
    for (int it = 0; it < 128; ++it) {
      float4 mm = m4[it], vv = v4[it];
      a += mm.x * vv.x + mm.y * vv.y + mm.z * vv.z + mm.w * vv.w;
    }
    ys[tid] = a;
  }
  __syncthreads();
  float acc;
  {
    const float* Qr = Q + (size_t)tid * 256;
    float qy = 0.f;
    for (int k = 0; k < 256; ++k) qy = fmaf(Qr[k], ys[k], qy);
    acc = qy * ys[tid];
  }
  if (tid < 128) {
    const float* Rr = R + (size_t)tid * 128;
    float ru = 0.f;
    for (int k = 0; k < 128; ++k) ru = fmaf(Rr[k], us[k], ru);
    acc += ru * us[tid];
  }
  float v = acc;
  v += __shfl_xor(v, 32);
  v += __shfl_xor(v, 16);
  v += __shfl_xor(v, 8);
  v += __shfl_xor(v, 4);
  v += __shfl_xor(v, 2);
  v += __shfl_xor(v, 1);
  if ((tid & 63) == 0) redw[tid >> 6] = v;
  __syncthreads();
  if (tid == 0) out[t] = redw[0] + redw[1] + redw[2] + redw[3];
}

// ---------------------------------------------------------------------------
extern "C" void kernel_launch(void* const* d_in, const int* in_sizes, int n_in,
                              void* d_out, int out_size, void* d_ws, size_t ws_size,
                              hipStream_t stream) {
  (void)in_sizes; (void)n_in; (void)out_size; (void)ws_size;
  const float* A = (const float*)d_in[0];
  const float* B = (const float*)d_in[1];
  const float* C = (const float*)d_in[2];
  const float* Q = (const float*)d_in[3];
  const float* R = (const float*)d_in[4];
  const float* Km = (const float*)d_in[5];
  const float* MT = (const float*)d_in[6];
  const float* Phi = (const float*)d_in[7];
  const float* sm = (const float*)d_in[8];
  const float* x0 = (const float*)d_in[9];

  float* ws = (float*)d_ws;
  float* Wfir = ws;                      // 2,097,152
  float* Pp = Wfir + 2097152;            // 4,194,304  (P[1..16])
  float* CApp = Pp + 4194304;            // 2,097,152  (CAp[1..16])
  float* W0CAp = CApp + 2097152;         // 1,048,576  (W0CA[1..16])
  float* Rnp = W0CAp + 1048576;          // 1,048,576  (Rn[1..16])
  float* AB33p = Rnp + 1048576;          // 1,114,112  (AB33[0..16])
  float* CAB33p = AB33p + 1114112;       //   557,056  (CAB33[0..16])
  float* W0CAB33p = CAB33p + 557056;     //   278,528  (W0CAB33[0..16])
  float* A16k = W0CAB33p + 278528;       //   262,144
  float* KCp = A16k + 262144;            //    65,536
  float* W0Cp = KCp + 65536;             //    65,536
  float* Aclp = W0Cp + 65536;            //   262,144
  float* M2g = Aclp + 262144;            // 1,048,576  (scratch after wfir)
  float* xh = M2g + 1048576;             //   524,288
  float* uh0 = xh + 524288;              //   139,264  ((64+1024)x128)
  float* eh = uh0 + 139264;              //   139,392  (1089x128)
  float* ynh = eh + 139392;              //   262,144
  float* dbnd = ynh + 262144;            //    33,280  (65x512)
  unsigned* arr = (unsigned*)(dbnd + 33280);  // NWG*32 u32

  float* scr0 = M2g;
  float* scr1 = M2g + 262144;
  float* scr2 = M2g + 524288;
  float* scr3 = M2g + 786432;

  auto gemm = [&](const float* X, const float* Y, float* Z, int M, int N, int Kd) {
    dim3 g(N / 64, M / 64);
    gemm_kernel<<<g, dim3(256), 0, stream>>>(X, Y, Z, M, N, Kd);
  };

  // ---- feedback closure ----
  gemm(Km, C, KCp, 128, 512, 256);       // KC
  gemm(B, KCp, scr0, 512, 512, 128);     // BKC
  axpy_acl<<<dim3(1024), dim3(256), 0, stream>>>(A, scr0, Aclp, Pp);  // Acl, P[1]
  init_kernel<<<dim3(2048), dim3(256), 0, stream>>>(x0, xh, eh, ynh, uh0, dbnd, arr);

  // ---- FIR bank ----
  m2_kernel<<<dim3(4096), dim3(256), 0, stream>>>(MT, sm, M2g);
  wfir_kernel<<<dim3(8192), dim3(256), 0, stream>>>(M2g, Phi, Wfir);
  gemm(Wfir, C, W0Cp, 128, 512, 256);    // W0C = W[0]@C

  // ---- open-loop A powers / A33B ----
  gemm(A, A, scr0, 512, 512, 512);        // A2
  gemm(scr0, scr0, scr1, 512, 512, 512);  // A4
  gemm(scr1, scr1, scr2, 512, 512, 512);  // A8
  gemm(scr2, scr2, A16k, 512, 512, 512);  // A16
  gemm(A16k, A16k, scr3, 512, 512, 512);  // A32
  gemm(A, B, scr0, 512, 128, 512);        // AB
  gemm(scr3, scr0, AB33p, 512, 128, 512); // AB33[0] = A^33 B
  gemm(A, AB33p, AB33p + 65536, 512, 128, 512);          // AB33[1]

  // ---- chain seeds (power 0/1) ----
  gemm(C, AB33p, CAB33p, 256, 128, 512);                  // CAB33[0]
  gemm(W0Cp, AB33p, W0CAB33p, 128, 128, 512);             // W0CAB33[0]
  gemm(C, A, CApp, 256, 512, 512);                        // CAp[1]
  gemm(W0Cp, A, W0CAp, 128, 512, 512);                    // W0CA[1]
  gemm(Aclp, B, Rnp, 512, 128, 512);                      // Rn[1]
  gemm(C, AB33p + 65536, CAB33p + 32768, 256, 128, 512);  // CAB33[1]
  gemm(W0Cp, AB33p + 65536, W0CAB33p + 16384, 128, 128, 512);  // W0CAB33[1]

  // ---- chains s=2..16 ----
  for (int s = 2; s <= 16; ++s)
    chainstep_kernel<<<dim3(156), dim3(256), 0, stream>>>(
        s, A, Aclp, Pp, CApp, W0CAp, Rnp, AB33p, CAB33p, W0CAB33p);

  // ---- main blocked loop ----
  main_kernel<<<dim3(NWG), dim3(TPB), 0, stream>>>(
      B, C, x0, Wfir, KCp, W0Cp, Pp, CApp, W0CAp, Rnp, AB33p, CAB33p,
      W0CAB33p, A16k, xh, uh0, eh, ynh, dbnd, arr);

  // ---- cost epilogue ----
  cost_kernel<<<dim3(1024), dim3(256), 0, stream>>>(C, Q, R, xh, uh0,
                                                    (float*)d_out);
}

// Round 6
// 3504.053 us; speedup vs baseline: 8.9373x; 1.3599x over previous
//
#include <hip/hip_runtime.h>

#define TPB 256
#define NWG 160
#define MAXJ 48

// ---------------------------------------------------------------------------
// Coherent (agent-scope, MALL-served) helpers: sc1 loads/stores, no fences.
// ---------------------------------------------------------------------------
__device__ __forceinline__ void cst(float* p, float v) {
  __hip_atomic_store(p, v, __ATOMIC_RELAXED, __HIP_MEMORY_SCOPE_AGENT);
}
__device__ __forceinline__ void cstu(unsigned* p, unsigned v) {
  __hip_atomic_store(p, v, __ATOMIC_RELAXED, __HIP_MEMORY_SCOPE_AGENT);
}
__device__ __forceinline__ float cld(const float* p) {
  return __hip_atomic_load(p, __ATOMIC_RELAXED, __HIP_MEMORY_SCOPE_AGENT);
}
__device__ __forceinline__ float2 cld2(const float* p) {
  unsigned long long u = __hip_atomic_load(
      reinterpret_cast<const unsigned long long*>(p), __ATOMIC_RELAXED,
      __HIP_MEMORY_SCOPE_AGENT);
  float2 v;
  __builtin_memcpy(&v, &u, 8);
  return v;
}

// ---------------------------------------------------------------------------
// Grid barrier: vmcnt drain (sc1 stores+atomics ack at coherence point),
// relaxed flag store, relaxed polls on padded slots. No cache maintenance.
// ---------------------------------------------------------------------------
__device__ __forceinline__ void grid_barrier(unsigned* __restrict__ arr,
                                             int bid, int tid, unsigned phase) {
  asm volatile("s_waitcnt vmcnt(0)" ::: "memory");
  __syncthreads();
  if (tid == 0)
    __hip_atomic_store(arr + (bid << 5), phase, __ATOMIC_RELAXED,
                       __HIP_MEMORY_SCOPE_AGENT);
  if (tid < NWG) {
    while (__hip_atomic_load(arr + (tid << 5), __ATOMIC_RELAXED,
                             __HIP_MEMORY_SCOPE_AGENT) < phase)
      __builtin_amdgcn_s_sleep(1);
  }
  __atomic_signal_fence(__ATOMIC_SEQ_CST);
  __syncthreads();
}

// ---------------------------------------------------------------------------
// Tiled fp32 GEMM tile body: Z[M x N] = X[M x K] @ Y[K x N], row-major.
// ---------------------------------------------------------------------------
__device__ void gemm_tile(const float* __restrict__ X, const float* __restrict__ Y,
                          float* __restrict__ Z, int M, int N, int Kd,
                          int mtile, int ntile) {
  __shared__ float Xs[16][65];
  __shared__ float Ys[16][65];
  const int tx = threadIdx.x & 15;
  const int ty = threadIdx.x >> 4;
  const int mbase = mtile * 64;
  const int nbase = ntile * 64;
  float acc[4][4] = {};
  for (int k0 = 0; k0 < Kd; k0 += 16) {
#pragma unroll
    for (int r = 0; r < 4; ++r) {
      int idx = threadIdx.x + 256 * r;
      int mm = idx >> 4, kk = idx & 15;
      int gm = mbase + mm, gk = k0 + kk;
      Xs[kk][mm] = (gm < M && gk < Kd) ? X[(size_t)gm * Kd + gk] : 0.f;
      int nn = idx & 63, k2 = idx >> 6;
      int gn = nbase + nn, gk2 = k0 + k2;
      Ys[k2][nn] = (gk2 < Kd && gn < N) ? Y[(size_t)gk2 * N + gn] : 0.f;
    }
    __syncthreads();
#pragma unroll
    for (int kk = 0; kk < 16; ++kk) {
      float xv[4], yv[4];
#pragma unroll
      for (int a = 0; a < 4; ++a) xv[a] = Xs[kk][ty * 4 + a];
#pragma unroll
      for (int b = 0; b < 4; ++b) yv[b] = Ys[kk][tx * 4 + b];
#pragma unroll
      for (int a = 0; a < 4; ++a)
#pragma unroll
        for (int b = 0; b < 4; ++b) acc[a][b] += xv[a] * yv[b];
    }
    __syncthreads();
  }
#pragma unroll
  for (int a = 0; a < 4; ++a) {
    int gm = mbase + ty * 4 + a;
    if (gm < M) {
#pragma unroll
      for (int b = 0; b < 4; ++b) {
        int gn = nbase + tx * 4 + b;
        if (gn < N) Z[(size_t)gm * N + gn] = acc[a][b];
      }
    }
  }
}

// ---------------------------------------------------------------------------
// Batched multi-GEMM: job table by value (<=48 jobs), one launch per level.
// xsel/ysel: 0=ws, 1=A, 2=B, 3=C, 4=Km.
// ---------------------------------------------------------------------------
struct JobBatch {
  int n;
  int start[MAXJ + 1];
  int xsel[MAXJ], xoff[MAXJ], ysel[MAXJ], yoff[MAXJ], zoff[MAXJ];
  int M[MAXJ], N[MAXJ], K[MAXJ];
};

__global__ __launch_bounds__(256) void multi_gemm(JobBatch jb,
    const float* __restrict__ A, const float* __restrict__ Bm,
    const float* __restrict__ C, const float* __restrict__ Km,
    float* __restrict__ ws) {
  int b = blockIdx.x;
  int j = 0;
  while (j < jb.n - 1 && b >= jb.start[j + 1]) ++j;
  int rel = b - jb.start[j];
  const float* bases[5] = {ws, A, Bm, C, Km};
  const float* X = bases[jb.xsel[j]] + jb.xoff[j];
  const float* Y = bases[jb.ysel[j]] + jb.yoff[j];
  float* Z = ws + jb.zoff[j];
  int tn = jb.N[j] >> 6;
  gemm_tile(X, Y, Z, jb.M[j], jb.N[j], jb.K[j], rel / tn, rel % tn);
}

// ---------------------------------------------------------------------------
__global__ __launch_bounds__(256) void m2_kernel(const float* __restrict__ MT,
    const float* __restrict__ sm, float* __restrict__ M2g) {
  int idx = blockIdx.x * 256 + threadIdx.x;
  if (idx >= 128 * 32 * 256) return;
  int q = idx & 255;
  int ci = idx >> 8;
  const float* base = MT + (size_t)ci * 32 * 256 + q;
  float acc = 0.f;
#pragma unroll
  for (int j = 0; j < 32; ++j) acc += base[j * 256] * sm[j];
  M2g[idx] = acc;
}

__global__ __launch_bounds__(256) void wfir_kernel(const float* __restrict__ M2g,
    const float* __restrict__ Phi, float* __restrict__ W) {
  int idx = blockIdx.x * 256 + threadIdx.x;  // j*32768 + c*256 + q
  if (idx >= 64 * 32768) return;
  int j = idx >> 15;
  int cq = idx & 32767;
  int c = cq >> 8;
  int q = cq & 255;
  float acc = 0.f;
#pragma unroll
  for (int i = 0; i < 32; ++i)
    acc = fmaf(Phi[(i << 6) | j], M2g[(size_t)(((c << 5) | i) << 8) | q], acc);
  W[idx] = acc;
}

// Acl = A - BKC; also copy into P[1] slot.
__global__ __launch_bounds__(256) void axpy_acl(const float* __restrict__ A,
    const float* __restrict__ BKC, float* __restrict__ Acl, float* __restrict__ P1) {
  int i = blockIdx.x * 256 + threadIdx.x;
  if (i < 262144) {
    float v = A[i] - BKC[i];
    Acl[i] = v;
    P1[i] = v;
  }
}

// ---------------------------------------------------------------------------
__global__ void init_kernel(const float* __restrict__ x0, float* __restrict__ xh,
    float* __restrict__ eh, float* __restrict__ ynh, float* __restrict__ uh0,
    float* __restrict__ dbnd, unsigned* __restrict__ arr) {
  int i = blockIdx.x * 256 + threadIdx.x;
  int stride = gridDim.x * 256;
  for (int k = i; k < 524288; k += stride) cst(xh + k, 0.f);
  for (int k = i; k < 139392; k += stride) cst(eh + k, 0.f);
  for (int k = i; k < 262144; k += stride) cst(ynh + k, 0.f);
  for (int k = i; k < 8192; k += stride) cst(uh0 + k, 0.f);  // 64 pad rows
  for (int k = i; k < NWG * 32; k += stride) cstu(arr + k, 0u);
  if (i < 512) cst(dbnd + i, x0[i]);
}

// padded smV index: quarter stride 132 floats kills 4-way bank conflicts
#define SVIDX(i) ((((i) >> 7) * 132) + ((i) & 127))

__device__ __forceinline__ void stagePad(float* dst, const float* src, int tid) {
  float2 v = cld2(src + (tid << 1));
  int i = tid << 1;
  int a = SVIDX(i);
  dst[a] = v.x;
  dst[a + 1] = v.y;
}

// ---------------------------------------------------------------------------
// Persistent main loop. 65 phases x 2 barriers. Phase ph, T=16*ph, Tp=T-16.
// sub-A roles:
//   WG   0.. 31 Yd : y_nat[T+s] += CAp[s] d_T        (s=bid>>1, 128-row half)
//   WG  32.. 47 Yu : y_nat[T+s] += sum_m CAB33[m] u_{T+s-m-34}
//   WG  48.. 63 Wd : e[T+s]     += W0CA[s] d_T
//   WG  64.. 71 Wu : e[T+s]     += sum_m W0CAB33[m] u_{T+s-m-34}
//   WG  72.. 87 Dt : dbnd[ph+1] = A^16 d_T + sum_m AB33[m] u_{T+15-m-33}
//   WG  88..119 Xp : x[Tp+s]    += P[s+1] x_{Tp-1}   (s=w>>1, 256-row half)
//   WG 120..151 Xr : x[Tp+s]    += sum_i Rn[i] e_{Tp+s-1-i}   (Rn[0]=B)
// sub-B roles:
//   WG   0..127 SC : e[T+s+j]   += W[j]·y_nat[T+s]  (j=1..63; c=WG; W in LDS)
//   WG 128..159 U  : u[Tp+s]    = -KC x_{Tp+s} + e_{Tp+s}
// ---------------------------------------------------------------------------
__global__ __launch_bounds__(TPB, 1) void main_kernel(
    const float* __restrict__ B, const float* __restrict__ C,
    const float* __restrict__ x0, const float* __restrict__ Wfir,
    const float* __restrict__ KC, const float* __restrict__ W0C,
    const float* __restrict__ Pp, const float* __restrict__ CApp,
    const float* __restrict__ W0CAp, const float* __restrict__ Rnp,
    const float* __restrict__ AB33p, const float* __restrict__ CAB33p,
    const float* __restrict__ W0CAB33p, const float* __restrict__ A16k,
    float* __restrict__ xh, float* __restrict__ uh0, float* __restrict__ eh,
    float* __restrict__ ynh, float* __restrict__ dbnd,
    unsigned* __restrict__ arr) {
  __shared__ float smA[64 * 256];   // SC: Wfir c-slice [j][q]
  __shared__ float smY[16 * 256];   // SC: y-block
  __shared__ float smV[528];        // staged d / x vector (padded quarters)
  __shared__ float smW[16 * 128];   // staged u/e window
  __shared__ float redsc[4][16];
  const int bid = blockIdx.x;
  const int tid = threadIdx.x;

  if (bid < 128) {
    for (int i = tid; i < 16384; i += TPB) {
      int j = i >> 8;
      smA[i] = (j >= 1) ? Wfir[(size_t)j * 32768 + bid * 256 + (i & 255)] : 0.f;
    }
  }
  __syncthreads();

  unsigned bcnt = 0;
#pragma unroll 1
  for (int ph = 0; ph <= 64; ++ph) {
    const int T = ph * 16;
    const int Tp = T - 16;

    // ================= sub-A =================
    if (bid < 32) {  // ---- Yd ----
      if (ph < 64) {
        const int s = bid >> 1;
        const int half = (bid & 1) << 7;
        stagePad(smV, dbnd + (size_t)ph * 512, tid);
        __syncthreads();
        const float* Mrow = (s == 0) ? C : (CApp + (size_t)(s - 1) * 131072);
        const int row = half + (tid >> 1);
        const int q0 = (tid & 1) * 2;
        const float4* m4 = (const float4*)(Mrow + (size_t)row * 512 + (tid & 1) * 256);
        const float4* v0 = (const float4*)(smV + q0 * 132);
        const float4* v1 = (const float4*)(smV + (q0 + 1) * 132);
        float a0 = 0.f, a1 = 0.f;
#pragma unroll
        for (int it = 0; it < 32; ++it) {
          float4 mm = m4[it], vv = v0[it];
          a0 += mm.x * vv.x + mm.y * vv.y + mm.z * vv.z + mm.w * vv.w;
        }
#pragma unroll
        for (int it = 0; it < 32; ++it) {
          float4 mm = m4[32 + it], vv = v1[it];
          a1 += mm.x * vv.x + mm.y * vv.y + mm.z * vv.z + mm.w * vv.w;
        }
        float a = a0 + a1;
        a += __shfl_down(a, 1);
        if ((tid & 1) == 0) atomicAdd(&ynh[(size_t)(T + s) * 256 + row], a);
        __syncthreads();
      }
    } else if (bid < 48) {  // ---- Yu ----
      if (ph < 64) {
        const int g = bid - 32;
        for (int i2 = tid; i2 < 1024; i2 += TPB) {
          float2 v = cld2(uh0 + (size_t)(64 + T - 33) * 128 + 2 * i2);
          smW[2 * i2] = v.x;
          smW[2 * i2 + 1] = v.y;
        }
        __syncthreads();
        const int row = g * 16 + (tid >> 4);
        const int l16 = tid & 15;
        const int qs = l16 * 8;
        float acc[16];
#pragma unroll
        for (int s = 0; s < 16; ++s) acc[s] = 0.f;
#pragma unroll
        for (int m = 0; m < 15; ++m) {
          const float4* cr = (const float4*)(CAB33p + (size_t)m * 32768 + (size_t)row * 128 + qs);
          float4 c0 = cr[0], c1 = cr[1];
#pragma unroll
          for (int s = 0; s < 16; ++s) {
            if (s > m) {
              const float* u = smW + (s - m - 1) * 128 + qs;
              acc[s] += c0.x * u[0] + c0.y * u[1] + c0.z * u[2] + c0.w * u[3] +
                        c1.x * u[4] + c1.y * u[5] + c1.z * u[6] + c1.w * u[7];
            }
          }
        }
#pragma unroll
        for (int s = 0; s < 16; ++s) {
          float v = acc[s];
          v += __shfl_xor(v, 8);
          v += __shfl_xor(v, 4);
          v += __shfl_xor(v, 2);
          v += __shfl_xor(v, 1);
          if (l16 == 0 && s >= 1) atomicAdd(&ynh[(size_t)(T + s) * 256 + row], v);
        }
        __syncthreads();
      }
    } else if (bid < 64) {  // ---- Wd ----
      if (ph < 64) {
        const int s = bid - 48;
        stagePad(smV, dbnd + (size_t)ph * 512, tid);
        __syncthreads();
        const float* Mrow = (s == 0) ? W0C : (W0CAp + (size_t)(s - 1) * 65536);
        const int row = tid >> 1;
        const int q0 = (tid & 1) * 2;
        const float4* m4 = (const float4*)(Mrow + (size_t)row * 512 + (tid & 1) * 256);
        const float4* v0 = (const float4*)(smV + q0 * 132);
        const float4* v1 = (const float4*)(smV + (q0 + 1) * 132);
        float a0 = 0.f, a1 = 0.f;
#pragma unroll
        for (int it = 0; it < 32; ++it) {
          float4 mm = m4[it], vv = v0[it];
          a0 += mm.x * vv.x + mm.y * vv.y + mm.z * vv.z + mm.w * vv.w;
        }
#pragma unroll
        for (int it = 0; it < 32; ++it) {
          float4 mm = m4[32 + it], vv = v1[it];
          a1 += mm.x * vv.x + mm.y * vv.y + mm.z * vv.z + mm.w * vv.w;
        }
        float a = a0 + a1;
        a += __shfl_down(a, 1);
        if ((tid & 1) == 0) atomicAdd(&eh[(size_t)(T + s) * 128 + row], a);
        __syncthreads();
      }
    } else if (bid < 72) {  // ---- Wu ----
      if (ph < 64) {
        const int g = bid - 64;
        for (int i2 = tid; i2 < 1024; i2 += TPB) {
          float2 v = cld2(uh0 + (size_t)(64 + T - 33) * 128 + 2 * i2);
          smW[2 * i2] = v.x;
          smW[2 * i2 + 1] = v.y;
        }
        __syncthreads();
        const int row = g * 16 + (tid >> 4);
        const int l16 = tid & 15;
        const int qs = l16 * 8;
        float acc[16];
#pragma unroll
        for (int s = 0; s < 16; ++s) acc[s] = 0.f;
#pragma unroll
        for (int m = 0; m < 15; ++m) {
          const float4* cr = (const float4*)(W0CAB33p + (size_t)m * 16384 + (size_t)row * 128 + qs);
          float4 c0 = cr[0], c1 = cr[1];
#pragma unroll
          for (int s = 0; s < 16; ++s) {
            if (s > m) {
              const float* u = smW + (s - m - 1) * 128 + qs;
              acc[s] += c0.x * u[0] + c0.y * u[1] + c0.z * u[2] + c0.w * u[3] +
                        c1.x * u[4] + c1.y * u[5] + c1.z * u[6] + c1.w * u[7];
            }
          }
        }
#pragma unroll
        for (int s = 0; s < 16; ++s) {
          float v = acc[s];
          v += __shfl_xor(v, 8);
          v += __shfl_xor(v, 4);
          v += __shfl_xor(v, 2);
          v += __shfl_xor(v, 1);
          if (l16 == 0 && s >= 1) atomicAdd(&eh[(size_t)(T + s) * 128 + row], v);
        }
        __syncthreads();
      }
    } else if (bid < 88) {  // ---- Dt ----
      if (ph < 64) {
        const int g = bid - 72;
        stagePad(smV, dbnd + (size_t)ph * 512, tid);
        for (int i2 = tid; i2 < 1024; i2 += TPB) {
          float2 v = cld2(uh0 + (size_t)(64 + T - 33) * 128 + 2 * i2);
          smW[2 * i2] = v.x;
          smW[2 * i2 + 1] = v.y;
        }
        __syncthreads();
        const int row = g * 32 + (tid >> 3);
        const int l8 = tid & 7;
        float a = 0.f;
        {
          const float4* m4 = (const float4*)(A16k + (size_t)row * 512 + l8 * 64);
          const float4* v4 = (const float4*)(smV + (l8 >> 1) * 132 + (l8 & 1) * 64);
#pragma unroll
          for (int it = 0; it < 16; ++it) {
            float4 mm = m4[it], vv = v4[it];
            a += mm.x * vv.x + mm.y * vv.y + mm.z * vv.z + mm.w * vv.w;
          }
        }
#pragma unroll
        for (int m = 0; m < 16; ++m) {
          const float4* m4 = (const float4*)(AB33p + (size_t)m * 65536 + (size_t)row * 128 + l8 * 16);
          const float4* v4 = (const float4*)(smW + (15 - m) * 128 + l8 * 16);
#pragma unroll
          for (int it = 0; it < 4; ++it) {
            float4 mm = m4[it], vv = v4[it];
            a += mm.x * vv.x + mm.y * vv.y + mm.z * vv.z + mm.w * vv.w;
          }
        }
        a += __shfl_down(a, 4);
        a += __shfl_down(a, 2);
        a += __shfl_down(a, 1);
        if (l8 == 0) cst(&dbnd[(size_t)(ph + 1) * 512 + row], a);
        __syncthreads();
      }
    } else if (bid < 120) {  // ---- Xp ----
      if (ph >= 1) {
        const int w = bid - 88;
        const int s = w >> 1;
        const int half = (w & 1) << 8;
        {
          const float* src = (ph == 1) ? x0 : (xh + (size_t)(Tp - 1) * 512);
          stagePad(smV, src, tid);
        }
        __syncthreads();
        const int pslot = (ph == 1) ? s : (s + 1);
        const int row = half + tid;
        if (pslot == 0) {
          atomicAdd(&xh[(size_t)(Tp + s) * 512 + row], smV[SVIDX(row)]);
        } else {
          const float* Mrow = Pp + (size_t)(pslot - 1) * 262144 + (size_t)row * 512;
          const float4* m4 = (const float4*)Mrow;
          float a0 = 0.f, a1 = 0.f, a2 = 0.f, a3 = 0.f;
          const float4* vq0 = (const float4*)(smV);
          const float4* vq1 = (const float4*)(smV + 132);
          const float4* vq2 = (const float4*)(smV + 264);
          const float4* vq3 = (const float4*)(smV + 396);
#pragma unroll
          for (int it = 0; it < 32; ++it) {
            float4 mm = m4[it], vv = vq0[it];
            a0 += mm.x * vv.x + mm.y * vv.y + mm.z * vv.z + mm.w * vv.w;
          }
#pragma unroll
          for (int it = 0; it < 32; ++it) {
            float4 mm = m4[32 + it], vv = vq1[it];
            a1 += mm.x * vv.x + mm.y * vv.y + mm.z * vv.z + mm.w * vv.w;
          }
#pragma unroll
          for (int it = 0; it < 32; ++it) {
            float4 mm = m4[64 + it], vv = vq2[it];
            a2 += mm.x * vv.x + mm.y * vv.y + mm.z * vv.z + mm.w * vv.w;
          }
#pragma unroll
          for (int it = 0; it < 32; ++it) {
            float4 mm = m4[96 + it], vv = vq3[it];
            a3 += mm.x * vv.x + mm.y * vv.y + mm.z * vv.z + mm.w * vv.w;
          }
          atomicAdd(&xh[(size_t)(Tp + s) * 512 + row], (a0 + a1) + (a2 + a3));
        }
        __syncthreads();
      }
    } else {  // ---- Xr (bid 120..151) ----
      if (ph >= 1 && bid < 152) {
        const int g = bid - 120;
        for (int i2 = tid; i2 < 1024; i2 += TPB) {
          int idx = 2 * i2;
          int r = idx >> 7;
          float2 v;
          if (ph == 1 && r == 0) {
            v.x = 0.f;
            v.y = 0.f;
          } else {
            v = cld2(eh + (size_t)(Tp - 1 + r) * 128 + (idx & 127));
          }
          smW[idx] = v.x;
          smW[idx + 1] = v.y;
        }
        __syncthreads();
        const int row = g * 16 + (tid >> 4);
        const int l16 = tid & 15;
        const int qs = l16 * 8;
        float acc[16];
#pragma unroll
        for (int s = 0; s < 16; ++s) acc[s] = 0.f;
#pragma unroll
        for (int i = 0; i < 16; ++i) {
          const float* Rrow = (i == 0) ? (B + (size_t)row * 128 + qs)
                                       : (Rnp + (size_t)(i - 1) * 65536 + (size_t)row * 128 + qs);
          const float4* cr = (const float4*)Rrow;
          float4 c0 = cr[0], c1 = cr[1];
#pragma unroll
          for (int s = 0; s < 16; ++s) {
            if (s >= i) {
              const float* e = smW + (s - i) * 128 + qs;
              acc[s] += c0.x * e[0] + c0.y * e[1] + c0.z * e[2] + c0.w * e[3] +
                        c1.x * e[4] + c1.y * e[5] + c1.z * e[6] + c1.w * e[7];
            }
          }
        }
#pragma unroll
        for (int s = 0; s < 16; ++s) {
          float v = acc[s];
          v += __shfl_xor(v, 8);
          v += __shfl_xor(v, 4);
          v += __shfl_xor(v, 2);
          v += __shfl_xor(v, 1);
          if (l16 == 0) atomicAdd(&xh[(size_t)(Tp + s) * 512 + row], v);
        }
        __syncthreads();
      }
    }

    grid_barrier(arr, bid, tid, ++bcnt);

    // ================= sub-B =================
    if (bid < 128) {  // ---- SC ----
      if (ph < 64) {
        const int c = bid;
        for (int i2 = tid; i2 < 2048; i2 += TPB) {
          float2 v = cld2(ynh + (size_t)T * 256 + 2 * i2);
          smY[2 * i2] = v.x;
          smY[2 * i2 + 1] = v.y;
        }
        __syncthreads();
        const int q = tid;
        float yreg[16];
#pragma unroll
        for (int s = 0; s < 16; ++s) yreg[s] = smY[s * 256 + q];
        const int wv = tid >> 6;
        const int lane = tid & 63;
#pragma unroll
        for (int kt = 0; kt < 5; ++kt) {
          const int r0 = 1 + 16 * kt;
          float wreg[31];
#pragma unroll
          for (int i = 0; i < 31; ++i) {
            const int j = r0 - 15 + i;
            wreg[i] = (j >= 1 && j <= 63) ? smA[j * 256 + q] : 0.f;
          }
          float acc[16];
#pragma unroll
          for (int a = 0; a < 16; ++a) acc[a] = 0.f;
#pragma unroll
          for (int a = 0; a < 16; ++a)
#pragma unroll
            for (int s = 0; s < 16; ++s) acc[a] += wreg[a + 15 - s] * yreg[s];
#pragma unroll
          for (int a = 0; a < 16; ++a) {
            float v = acc[a];
            v += __shfl_xor(v, 32);
            v += __shfl_xor(v, 16);
            v += __shfl_xor(v, 8);
            v += __shfl_xor(v, 4);
            v += __shfl_xor(v, 2);
            v += __shfl_xor(v, 1);
            if (lane == 0) redsc[wv][a] = v;
          }
          __syncthreads();
          if (tid < 16) {
            float sum = redsc[0][tid] + redsc[1][tid] + redsc[2][tid] + redsc[3][tid];
            atomicAdd(&eh[(size_t)(T + r0 + tid) * 128 + c], sum);
          }
          __syncthreads();
        }
      }
    } else {  // ---- U (bid 128..159) ----
      if (ph >= 1) {
        const int g = bid - 128;
        const int s = g >> 1;
        const int ch = (g & 1) * 64;
        const int t = Tp + s;
        stagePad(smV, xh + (size_t)t * 512, tid);
        __syncthreads();
        const int row = ch + (tid >> 2);
        const int q0 = tid & 3;
        const float4* m4 = (const float4*)(KC + (size_t)row * 512 + q0 * 128);
        const float4* v4 = (const float4*)(smV + q0 * 132);
        float a = 0.f;
#pragma unroll
        for (int it = 0; it < 32; ++it) {
          float4 mm = m4[it], vv = v4[it];
          a += mm.x * vv.x + mm.y * vv.y + mm.z * vv.z + mm.w * vv.w;
        }
        a += __shfl_down(a, 2);
        a += __shfl_down(a, 1);
        if ((tid & 3) == 0) {
          float u = cld(&eh[(size_t)t * 128 + row]) - a;
          cst(&uh0[(size_t)(64 + t) * 128 + row], u);
        }
        __syncthreads();
      }
    }

    grid_barrier(arr, bid, tid, ++bcnt);
  }
}

// ---------------------------------------------------------------------------
// Epilogue: y_obs_t = C x_t; cost_t = y'Q y + u'R u.  (one WG per t)
// ---------------------------------------------------------------------------
__global__ __launch_bounds__(256) void cost_kernel(const float* __restrict__ C,
    const float* __restrict__ Q, const float* __restrict__ R,
    const float* __restrict__ xh, const float* __restrict__ uh0,
    float* __restrict__ out) {
  __shared__ float xs[512];
  __shared__ float ys[256];
  __shared__ float us[128];
  __shared__ float redw[4];
  const int t = blockIdx.x;
  const int tid = threadIdx.x;
  {
    float2 v = cld2(xh + (size_t)t * 512 + 2 * tid);
    xs[2 * tid] = v.x;
    xs[2 * tid + 1] = v.y;
  }
  if (tid < 64) {
    float2 v = cld2(uh0 + (size_t)(64 + t) * 128 + 2 * tid);
    us[2 * tid] = v.x;
    us[2 * tid + 1] = v.y;
  }
  __syncthreads();
  {
    const float4* m4 = (const float4*)(C + (size_t)tid * 512);
    const float4* v4 = (const float4*)xs;
    float a = 0.f;
    for (int it = 0; it < 128; ++it) {
      float4 mm = m4[it], vv = v4[it];
      a += mm.x * vv.x + mm.y * vv.y + mm.z * vv.z + mm.w * vv.w;
    }
    ys[tid] = a;
  }
  __syncthreads();
  float acc;
  {
    const float* Qr = Q + (size_t)tid * 256;
    float qy = 0.f;
    for (int k = 0; k < 256; ++k) qy = fmaf(Qr[k], ys[k], qy);
    acc = qy * ys[tid];
  }
  if (tid < 128) {
    const float* Rr = R + (size_t)tid * 128;
    float ru = 0.f;
    for (int k = 0; k < 128; ++k) ru = fmaf(Rr[k], us[k], ru);
    acc += ru * us[tid];
  }
  float v = acc;
  v += __shfl_xor(v, 32);
  v += __shfl_xor(v, 16);
  v += __shfl_xor(v, 8);
  v += __shfl_xor(v, 4);
  v += __shfl_xor(v, 2);
  v += __shfl_xor(v, 1);
  if ((tid & 63) == 0) redw[tid >> 6] = v;
  __syncthreads();
  if (tid == 0) out[t] = redw[0] + redw[1] + redw[2] + redw[3];
}

// ---------------------------------------------------------------------------
extern "C" void kernel_launch(void* const* d_in, const int* in_sizes, int n_in,
                              void* d_out, int out_size, void* d_ws, size_t ws_size,
                              hipStream_t stream) {
  (void)in_sizes; (void)n_in; (void)out_size; (void)ws_size;
  const float* A = (const float*)d_in[0];
  const float* B = (const float*)d_in[1];
  const float* C = (const float*)d_in[2];
  const float* Q = (const float*)d_in[3];
  const float* R = (const float*)d_in[4];
  const float* Km = (const float*)d_in[5];
  const float* MT = (const float*)d_in[6];
  const float* Phi = (const float*)d_in[7];
  const float* sm = (const float*)d_in[8];
  const float* x0 = (const float*)d_in[9];

  float* ws = (float*)d_ws;
  // ---- ws layout (float offsets) ----
  const int oWfir = 0;               // 2,097,152
  const int oPp = 2097152;           // 16 x 262144 (P[1..16])
  const int oCApp = 6291456;         // 16 x 131072 (CA[1..16])
  const int oW0CAp = 8388608;        // 16 x 65536  (W0CA[1..16])
  const int oRnp = 9437184;          // 16 x 65536  (Rn[1..16])
  const int oAB33 = 10485760;        // 17 x 65536  (AB33[0..16]; slots 0-3 alias BKC early)
  const int oCAB33 = 11599872;       // 17 x 32768
  const int oW0CAB33 = 12156928;     // 17 x 16384
  const int oA16 = 12435456;         // 262144
  const int oKC = 12697600;          // 65536
  const int oW0C = 12763136;         // 65536
  const int oAcl = 12828672;         // 262144
  const int oM2 = 13090816;          // 1,048,576 (A2/A4/A8/A32 alias after wfir)
  const int oA2 = oM2, oA4 = oM2 + 262144, oA8 = oM2 + 524288, oA32 = oM2 + 786432;
  const int oApB = 14139392;         // 16 x 65536 (ApB[1..16])
  const int oxh = 15187968;          // 524288
  const int ouh0 = 15712256;         // 139264
  const int oeh = 15851520;          // 139392
  const int oynh = 15990912;         // 262144
  const int odbnd = 16253056;        // 33280
  const int oarr = 16286336;         // NWG*32 u32
  const int oBKC = oAB33;            // temp alias (dead before AB33 written)

  float* xh = ws + oxh;
  float* uh0 = ws + ouh0;
  float* eh = ws + oeh;
  float* ynh = ws + oynh;
  float* dbnd = ws + odbnd;
  unsigned* arr = (unsigned*)(ws + oarr);

  JobBatch jb;
  jb.n = 0;
  jb.start[0] = 0;
  auto J = [&](int xs_, int xo, int ys_, int yo, int zo, int M, int N, int K) {
    int i = jb.n++;
    jb.xsel[i] = xs_; jb.xoff[i] = xo; jb.ysel[i] = ys_; jb.yoff[i] = yo;
    jb.zoff[i] = zo; jb.M[i] = M; jb.N[i] = N; jb.K[i] = K;
    jb.start[i + 1] = jb.start[i] + (M >> 6) * (N >> 6);
  };
  auto L = [&]() {
    multi_gemm<<<dim3(jb.start[jb.n]), dim3(256), 0, stream>>>(jb, A, B, C, Km, ws);
    jb.n = 0;
    jb.start[0] = 0;
  };

  // ---- FIR bank (must precede A2 aliasing of M2) ----
  m2_kernel<<<dim3(4096), dim3(256), 0, stream>>>(MT, sm, ws + oM2);
  wfir_kernel<<<dim3(8192), dim3(256), 0, stream>>>(ws + oM2, Phi, ws + oWfir);

  // ---- L1 ----
  J(4, 0, 3, 0, oKC, 128, 512, 256);        // KC = Km@C
  J(1, 0, 1, 0, oA2, 512, 512, 512);        // A2
  J(1, 0, 2, 0, oApB, 512, 128, 512);       // ApB[1] = A@B
  J(3, 0, 1, 0, oCApp, 256, 512, 512);      // CA[1] = C@A
  L();
  // ---- L2 ----
  J(2, 0, 0, oKC, oBKC, 512, 512, 128);     // BKC = B@KC
  J(0, oA2, 0, oA2, oA4, 512, 512, 512);    // A4
  J(0, oCApp, 1, 0, oCApp + 131072, 256, 512, 512);  // CA[2]
  J(1, 0, 0, oApB, oApB + 65536, 512, 128, 512);     // ApB[2]
  J(0, oWfir, 3, 0, oW0C, 128, 512, 256);   // W0C = W[0]@C
  L();
  axpy_acl<<<dim3(1024), dim3(256), 0, stream>>>(A, ws + oBKC, ws + oAcl, ws + oPp);
  // ---- L3 ----
  J(0, oA4, 0, oA4, oA8, 512, 512, 512);                       // A8
  J(0, oPp, 0, oPp, oPp + 262144, 512, 512, 512);              // P[2]
  J(0, oCApp, 0, oA2, oCApp + 2 * 131072, 256, 512, 512);      // CA[3]
  J(0, oCApp + 131072, 0, oA2, oCApp + 3 * 131072, 256, 512, 512);  // CA[4]
  J(0, oW0C, 1, 0, oW0CAp, 128, 512, 512);                     // W0CA[1]
  J(0, oW0C, 0, oA2, oW0CAp + 65536, 128, 512, 512);           // W0CA[2]
  J(0, oA2, 0, oApB, oApB + 2 * 65536, 512, 128, 512);         // ApB[3]
  J(0, oA2, 0, oApB + 65536, oApB + 3 * 65536, 512, 128, 512); // ApB[4]
  L();
  // ---- L4 ----
  J(0, oA8, 0, oA8, oA16, 512, 512, 512);                      // A16
  J(0, oPp + 262144, 0, oPp, oPp + 2 * 262144, 512, 512, 512); // P[3]
  J(0, oPp + 262144, 0, oPp + 262144, oPp + 3 * 262144, 512, 512, 512);  // P[4]
  for (int i = 1; i <= 4; ++i)                                 // CA[5..8]
    J(0, oCApp + (i - 1) * 131072, 0, oA4, oCApp + (i + 3) * 131072, 256, 512, 512);
  for (int i = 1; i <= 2; ++i)                                 // W0CA[3,4]
    J(0, oW0CAp + (i - 1) * 65536, 0, oA2, oW0CAp + (i + 1) * 65536, 128, 512, 512);
  for (int i = 1; i <= 4; ++i)                                 // ApB[5..8]
    J(0, oA4, 0, oApB + (i - 1) * 65536, oApB + (i + 3) * 65536, 512, 128, 512);
  L();
  // ---- L5 ----
  J(0, oA16, 0, oA16, oA32, 512, 512, 512);                    // A32
  for (int i = 1; i <= 4; ++i)                                 // P[5..8]
    J(0, oPp + 3 * 262144, 0, oPp + (i - 1) * 262144, oPp + (i + 3) * 262144, 512, 512, 512);
  for (int i = 1; i <= 8; ++i)                                 // CA[9..16]
    J(0, oCApp + (i - 1) * 131072, 0, oA8, oCApp + (i + 7) * 131072, 256, 512, 512);
  for (int i = 1; i <= 4; ++i)                                 // W0CA[5..8]
    J(0, oW0CAp + (i - 1) * 65536, 0, oA4, oW0CAp + (i + 3) * 65536, 128, 512, 512);
  for (int i = 1; i <= 8; ++i)                                 // ApB[9..16]
    J(0, oA8, 0, oApB + (i - 1) * 65536, oApB + (i + 7) * 65536, 512, 128, 512);
  for (int i = 1; i <= 4; ++i)                                 // Rn[1..4]
    J(0, oPp + (i - 1) * 262144, 2, 0, oRnp + (i - 1) * 65536, 512, 128, 512);
  L();
  // ---- L6 ----
  for (int i = 1; i <= 8; ++i)                                 // P[9..16]
    J(0, oPp + 7 * 262144, 0, oPp + (i - 1) * 262144, oPp + (i + 7) * 262144, 512, 512, 512);
  for (int i = 1; i <= 8; ++i)                                 // W0CA[9..16]
    J(0, oW0CAp + (i - 1) * 65536, 0, oA8, oW0CAp + (i + 7) * 65536, 128, 512, 512);
  for (int m = 0; m <= 15; ++m)                                // AB33[0..15]
    J(0, oA32, 0, oApB + m * 65536, oAB33 + m * 65536, 512, 128, 512);
  for (int i = 5; i <= 8; ++i)                                 // Rn[5..8]
    J(0, oPp + (i - 1) * 262144, 2, 0, oRnp + (i - 1) * 65536, 512, 128, 512);
  L();
  // ---- L7 ----
  for (int m = 0; m <= 14; ++m)                                // CAB33[0..14]
    J(3, 0, 0, oAB33 + m * 65536, oCAB33 + m * 32768, 256, 128, 512);
  for (int m = 0; m <= 14; ++m)                                // W0CAB33[0..14]
    J(0, oW0C, 0, oAB33 + m * 65536, oW0CAB33 + m * 16384, 128, 128, 512);
  for (int i = 9; i <= 15; ++i)                                // Rn[9..15]
    J(0, oPp + (i - 1) * 262144, 2, 0, oRnp + (i - 1) * 65536, 512, 128, 512);
  L();

  init_kernel<<<dim3(2048), dim3(256), 0, stream>>>(x0, xh, eh, ynh, uh0, dbnd, arr);

  main_kernel<<<dim3(NWG), dim3(TPB), 0, stream>>>(
      B, C, x0, ws + oWfir, ws + oKC, ws + oW0C, ws + oPp, ws + oCApp,
      ws + oW0CAp, ws + oRnp, ws + oAB33, ws + oCAB33, ws + oW0CAB33,
      ws + oA16, xh, uh0, eh, ynh, dbnd, arr);

  cost_kernel<<<dim3(1024), dim3(256), 0, stream>>>(C, Q, R, xh, uh0,
                                                    (float*)d_out);
}

// Round 7
// 3324.894 us; speedup vs baseline: 9.4189x; 1.0539x over previous
//
#include <hip/hip_runtime.h>

#define TPB 256
#define NWG 214
#define MAXJ 48

// ---------------------------------------------------------------------------
// Coherent (agent-scope, MALL-served) helpers: sc1 loads/stores, no fences.
// ---------------------------------------------------------------------------
__device__ __forceinline__ void cst(float* p, float v) {
  __hip_atomic_store(p, v, __ATOMIC_RELAXED, __HIP_MEMORY_SCOPE_AGENT);
}
__device__ __forceinline__ void cstu(unsigned* p, unsigned v) {
  __hip_atomic_store(p, v, __ATOMIC_RELAXED, __HIP_MEMORY_SCOPE_AGENT);
}
__device__ __forceinline__ float cld(const float* p) {
  return __hip_atomic_load(p, __ATOMIC_RELAXED, __HIP_MEMORY_SCOPE_AGENT);
}
__device__ __forceinline__ float2 cld2(const float* p) {
  unsigned long long u = __hip_atomic_load(
      reinterpret_cast<const unsigned long long*>(p), __ATOMIC_RELAXED,
      __HIP_MEMORY_SCOPE_AGENT);
  float2 v;
  __builtin_memcpy(&v, &u, 8);
  return v;
}

// ---------------------------------------------------------------------------
// Grid barrier: vmcnt drain, relaxed flag store, relaxed poll. No cache ops.
// ---------------------------------------------------------------------------
__device__ __forceinline__ void grid_barrier(unsigned* __restrict__ arr,
                                             int bid, int tid, unsigned phase) {
  asm volatile("s_waitcnt vmcnt(0)" ::: "memory");
  __syncthreads();
  if (tid == 0)
    __hip_atomic_store(arr + (bid << 5), phase, __ATOMIC_RELAXED,
                       __HIP_MEMORY_SCOPE_AGENT);
  if (tid < NWG) {
    while (__hip_atomic_load(arr + (tid << 5), __ATOMIC_RELAXED,
                             __HIP_MEMORY_SCOPE_AGENT) < phase)
      __builtin_amdgcn_s_sleep(1);
  }
  __atomic_signal_fence(__ATOMIC_SEQ_CST);
  __syncthreads();
}

// ---------------------------------------------------------------------------
// Tiled fp32 GEMM tile body: Z[M x N] = X[M x K] @ Y[K x N], row-major.
// ---------------------------------------------------------------------------
__device__ void gemm_tile(const float* __restrict__ X, const float* __restrict__ Y,
                          float* __restrict__ Z, int M, int N, int Kd,
                          int mtile, int ntile) {
  __shared__ float Xs[16][65];
  __shared__ float Ys[16][65];
  const int tx = threadIdx.x & 15;
  const int ty = threadIdx.x >> 4;
  const int mbase = mtile * 64;
  const int nbase = ntile * 64;
  float acc[4][4] = {};
  for (int k0 = 0; k0 < Kd; k0 += 16) {
#pragma unroll
    for (int r = 0; r < 4; ++r) {
      int idx = threadIdx.x + 256 * r;
      int mm = idx >> 4, kk = idx & 15;
      int gm = mbase + mm, gk = k0 + kk;
      Xs[kk][mm] = (gm < M && gk < Kd) ? X[(size_t)gm * Kd + gk] : 0.f;
      int nn = idx & 63, k2 = idx >> 6;
      int gn = nbase + nn, gk2 = k0 + k2;
      Ys[k2][nn] = (gk2 < Kd && gn < N) ? Y[(size_t)gk2 * N + gn] : 0.f;
    }
    __syncthreads();
#pragma unroll
    for (int kk = 0; kk < 16; ++kk) {
      float xv[4], yv[4];
#pragma unroll
      for (int a = 0; a < 4; ++a) xv[a] = Xs[kk][ty * 4 + a];
#pragma unroll
      for (int b = 0; b < 4; ++b) yv[b] = Ys[kk][tx * 4 + b];
#pragma unroll
      for (int a = 0; a < 4; ++a)
#pragma unroll
        for (int b = 0; b < 4; ++b) acc[a][b] += xv[a] * yv[b];
    }
    __syncthreads();
  }
#pragma unroll
  for (int a = 0; a < 4; ++a) {
    int gm = mbase + ty * 4 + a;
    if (gm < M) {
#pragma unroll
      for (int b = 0; b < 4; ++b) {
        int gn = nbase + tx * 4 + b;
        if (gn < N) Z[(size_t)gm * N + gn] = acc[a][b];
      }
    }
  }
}

// ---------------------------------------------------------------------------
// Batched multi-GEMM. xsel/ysel: 0=ws, 1=A, 2=B, 3=C, 4=Km.
// ---------------------------------------------------------------------------
struct JobBatch {
  int n;
  int start[MAXJ + 1];
  int xsel[MAXJ], xoff[MAXJ], ysel[MAXJ], yoff[MAXJ], zoff[MAXJ];
  int M[MAXJ], N[MAXJ], K[MAXJ];
};

__global__ __launch_bounds__(256) void multi_gemm(JobBatch jb,
    const float* __restrict__ A, const float* __restrict__ Bm,
    const float* __restrict__ C, const float* __restrict__ Km,
    float* __restrict__ ws) {
  int b = blockIdx.x;
  int j = 0;
  while (j < jb.n - 1 && b >= jb.start[j + 1]) ++j;
  int rel = b - jb.start[j];
  const float* bases[5] = {ws, A, Bm, C, Km};
  const float* X = bases[jb.xsel[j]] + jb.xoff[j];
  const float* Y = bases[jb.ysel[j]] + jb.yoff[j];
  float* Z = ws + jb.zoff[j];
  int tn = jb.N[j] >> 6;
  gemm_tile(X, Y, Z, jb.M[j], jb.N[j], jb.K[j], rel / tn, rel % tn);
}

// ---------------------------------------------------------------------------
__global__ __launch_bounds__(256) void m2_kernel(const float* __restrict__ MT,
    const float* __restrict__ sm, float* __restrict__ M2g) {
  int idx = blockIdx.x * 256 + threadIdx.x;
  if (idx >= 128 * 32 * 256) return;
  int q = idx & 255;
  int ci = idx >> 8;
  const float* base = MT + (size_t)ci * 32 * 256 + q;
  float acc = 0.f;
#pragma unroll
  for (int j = 0; j < 32; ++j) acc += base[j * 256] * sm[j];
  M2g[idx] = acc;
}

__global__ __launch_bounds__(256) void wfir_kernel(const float* __restrict__ M2g,
    const float* __restrict__ Phi, float* __restrict__ W) {
  int idx = blockIdx.x * 256 + threadIdx.x;  // j*32768 + c*256 + q
  if (idx >= 64 * 32768) return;
  int j = idx >> 15;
  int cq = idx & 32767;
  int c = cq >> 8;
  int q = cq & 255;
  float acc = 0.f;
#pragma unroll
  for (int i = 0; i < 32; ++i)
    acc = fmaf(Phi[(i << 6) | j], M2g[(size_t)(((c << 5) | i) << 8) | q], acc);
  W[idx] = acc;
}

__global__ __launch_bounds__(256) void axpy_acl(const float* __restrict__ A,
    const float* __restrict__ BKC, float* __restrict__ Acl, float* __restrict__ P1) {
  int i = blockIdx.x * 256 + threadIdx.x;
  if (i < 262144) {
    float v = A[i] - BKC[i];
    Acl[i] = v;
    P1[i] = v;
  }
}

// ---------------------------------------------------------------------------
__global__ void init_kernel(const float* __restrict__ x0, float* __restrict__ xh,
    float* __restrict__ eh, float* __restrict__ ynh, float* __restrict__ uh0,
    float* __restrict__ dbnd, unsigned* __restrict__ arr) {
  int i = blockIdx.x * 256 + threadIdx.x;
  int stride = gridDim.x * 256;
  for (int k = i; k < 524288; k += stride) cst(xh + k, 0.f);
  for (int k = i; k < 139264; k += stride) cst(eh + k, 0.f);
  for (int k = i; k < 262144; k += stride) cst(ynh + k, 0.f);
  for (int k = i; k < 8192; k += stride) cst(uh0 + k, 0.f);  // 64 pad rows
  for (int k = i; k < NWG * 32; k += stride) cstu(arr + k, 0u);
  if (i < 512) cst(dbnd + i, x0[i]);
}

// ---------------------------------------------------------------------------
// Persistent main loop: 131 phases x ONE barrier. Phase ph, T=8*ph.
// All roles read only data complete by end of phase ph-1 (lag schedule):
//   bid   0..127 SC : e[Ty+r] += W[r-s]·y_nat[Ty+s], Ty=T-8   (y block ph-1)
//   bid 128..143 Yd : y_nat[T+s] += CA[s] d_T                 (block ph)
//   bid 144..150 Yu : y_nat[T+s] += sum_m CAB33[m] u[T+s-m-34]
//   bid 151..158 Wd : e[T+s]     += W0CA[s] d_T
//   bid 159..165 Wu : e[T+s]     += sum_m W0CAB33[m] u[T+s-m-34]
//   bid 166..173 Dt : dbnd[ph+1] = A8 d_T + sum_m AB33[m] u[T-26-m]
//   bid 174..189 Xp : x[Tq+s] += P[s+1] x[Tq-1], Tq=T-16      (block ph-2)
//   bid 190..205 Xr : x[Tq+s] += sum_i Rn[i] e[Tq+s-1-i]
//   bid 206..213 U  : u[Tu+s] = e[Tu+s] - KC x[Tu+s], Tu=T-24 (block ph-3)
// Maps stay in (per-XCD) L2: total map set ~21 MB < 32 MB aggregate.
// ---------------------------------------------------------------------------
__global__ __launch_bounds__(TPB, 1) void main_kernel(
    const float* __restrict__ B, const float* __restrict__ C,
    const float* __restrict__ x0, const float* __restrict__ Wfir,
    const float* __restrict__ KC, const float* __restrict__ W0C,
    const float* __restrict__ Pp, const float* __restrict__ CAp,
    const float* __restrict__ W0CAp, const float* __restrict__ Rnp,
    const float* __restrict__ AB33p, const float* __restrict__ CAB33p,
    const float* __restrict__ W0CAB33p, const float* __restrict__ A8k,
    float* __restrict__ xh, float* __restrict__ uh0, float* __restrict__ eh,
    float* __restrict__ ynh, float* __restrict__ dbnd,
    unsigned* __restrict__ arr) {
  __shared__ float smA[64 * 256];  // SC: Wfir c-slice [j][q], row 0 = zeros
  __shared__ float smY[8 * 256];   // SC: y block
  __shared__ float smV[512];       // d / x seed (broadcast-read)
  __shared__ float smW[8 * 128];   // u / e window
  __shared__ float smVx[8 * 516];  // U: 8 x-vectors (padded stride)
  __shared__ float redsc[4][16];
  const int bid = blockIdx.x;
  const int tid = threadIdx.x;

  if (bid < 128) {
    for (int i = tid; i < 16384; i += TPB) {
      int j = i >> 8;
      smA[i] = (j >= 1) ? Wfir[(size_t)j * 32768 + bid * 256 + (i & 255)] : 0.f;
    }
  }
  __syncthreads();

#pragma unroll 1
  for (int ph = 0; ph <= 130; ++ph) {
    const int T = ph * 8;

    if (bid < 128) {  // ---- SC ----
      if (ph >= 1 && ph < 129) {
        const int Ty = T - 8;
        const int c = bid;
        for (int i2 = tid; i2 < 1024; i2 += TPB) {
          float2 v = cld2(ynh + (size_t)Ty * 256 + 2 * i2);
          smY[2 * i2] = v.x;
          smY[2 * i2 + 1] = v.y;
        }
        __syncthreads();
        const int q = tid;
        float yreg[8];
#pragma unroll
        for (int s = 0; s < 8; ++s) yreg[s] = smY[s * 256 + q];
        const int wv = tid >> 6;
        const int lane = tid & 63;
#pragma unroll
        for (int kt = 0; kt < 5; ++kt) {
          const int r0 = 1 + 16 * kt;
          float wreg[23];
#pragma unroll
          for (int i = 0; i < 23; ++i) {
            const int j = r0 - 7 + i;
            wreg[i] = (j >= 1 && j <= 63) ? smA[j * 256 + q] : 0.f;
          }
          float acc[16];
#pragma unroll
          for (int a = 0; a < 16; ++a) acc[a] = 0.f;
#pragma unroll
          for (int a = 0; a < 16; ++a)
#pragma unroll
            for (int s = 0; s < 8; ++s) acc[a] += wreg[a + 7 - s] * yreg[s];
#pragma unroll
          for (int a = 0; a < 16; ++a) {
            float v = acc[a];
            v += __shfl_xor(v, 32);
            v += __shfl_xor(v, 16);
            v += __shfl_xor(v, 8);
            v += __shfl_xor(v, 4);
            v += __shfl_xor(v, 2);
            v += __shfl_xor(v, 1);
            if (lane == 0) redsc[wv][a] = v;
          }
          __syncthreads();
          if (tid < 16) {
            const int r = r0 + tid;
            if (r <= 70) {
              float sum = redsc[0][tid] + redsc[1][tid] + redsc[2][tid] + redsc[3][tid];
              atomicAdd(&eh[(size_t)(Ty + r) * 128 + c], sum);
            }
          }
          __syncthreads();
        }
      }
    } else if (bid < 144) {  // ---- Yd ----
      if (ph < 128) {
        const int r = bid - 128;
        const int s = r >> 1;
        const int half = (r & 1) << 7;
        {
          float2 v = cld2(dbnd + (size_t)ph * 512 + 2 * tid);
          smV[2 * tid] = v.x;
          smV[2 * tid + 1] = v.y;
        }
        __syncthreads();
        const float* Mrow = (s == 0) ? C : (CAp + (size_t)(s - 1) * 131072);
        const int row = half + (tid >> 1);
        const int seg = tid & 1;
        const float4* m4 = (const float4*)(Mrow + (size_t)row * 512 + seg * 256);
        const float4* v4 = (const float4*)(smV + seg * 256);
        float a = 0.f;
#pragma unroll
        for (int it = 0; it < 64; ++it) {
          float4 mm = m4[it], vv = v4[it];
          a += mm.x * vv.x + mm.y * vv.y + mm.z * vv.z + mm.w * vv.w;
        }
        a += __shfl_down(a, 1);
        if (seg == 0) atomicAdd(&ynh[(size_t)(T + s) * 256 + row], a);
        __syncthreads();
      }
    } else if (bid < 151) {  // ---- Yu ----
      if (ph < 128) {
        const int m = bid - 144;
        for (int i2 = tid; i2 < 512; i2 += TPB) {
          float2 v = cld2(uh0 + (size_t)(64 + T - 33) * 128 + 2 * i2);
          smW[2 * i2] = v.x;
          smW[2 * i2 + 1] = v.y;
        }
        __syncthreads();
        const int row = tid;  // 256 rows
        const float4* m4 = (const float4*)(CAB33p + (size_t)m * 32768 + (size_t)row * 128);
        for (int s = m + 1; s < 8; ++s) {
          const float4* u4 = (const float4*)(smW + (s - m - 1) * 128);
          float a = 0.f;
#pragma unroll
          for (int it = 0; it < 32; ++it) {
            float4 mm = m4[it], vv = u4[it];
            a += mm.x * vv.x + mm.y * vv.y + mm.z * vv.z + mm.w * vv.w;
          }
          atomicAdd(&ynh[(size_t)(T + s) * 256 + row], a);
        }
        __syncthreads();
      }
    } else if (bid < 159) {  // ---- Wd ----
      if (ph < 128) {
        const int s = bid - 151;
        {
          float2 v = cld2(dbnd + (size_t)ph * 512 + 2 * tid);
          smV[2 * tid] = v.x;
          smV[2 * tid + 1] = v.y;
        }
        __syncthreads();
        const float* Mrow = (s == 0) ? W0C : (W0CAp + (size_t)(s - 1) * 65536);
        const int row = tid >> 1;
        const int seg = tid & 1;
        const float4* m4 = (const float4*)(Mrow + (size_t)row * 512 + seg * 256);
        const float4* v4 = (const float4*)(smV + seg * 256);
        float a = 0.f;
#pragma unroll
        for (int it = 0; it < 64; ++it) {
          float4 mm = m4[it], vv = v4[it];
          a += mm.x * vv.x + mm.y * vv.y + mm.z * vv.z + mm.w * vv.w;
        }
        a += __shfl_down(a, 1);
        if (seg == 0) atomicAdd(&eh[(size_t)(T + s) * 128 + row], a);
        __syncthreads();
      }
    } else if (bid < 166) {  // ---- Wu ----
      if (ph < 128) {
        const int m = bid - 159;
        for (int i2 = tid; i2 < 512; i2 += TPB) {
          float2 v = cld2(uh0 + (size_t)(64 + T - 33) * 128 + 2 * i2);
          smW[2 * i2] = v.x;
          smW[2 * i2 + 1] = v.y;
        }
        __syncthreads();
        const int row = tid >> 1;
        const int seg = tid & 1;
        const float4* m4 = (const float4*)(W0CAB33p + (size_t)m * 16384 + (size_t)row * 128 + seg * 64);
        for (int s = m + 1; s < 8; ++s) {
          const float4* u4 = (const float4*)(smW + (s - m - 1) * 128 + seg * 64);
          float a = 0.f;
#pragma unroll
          for (int it = 0; it < 16; ++it) {
            float4 mm = m4[it], vv = u4[it];
            a += mm.x * vv.x + mm.y * vv.y + mm.z * vv.z + mm.w * vv.w;
          }
          a += __shfl_down(a, 1);
          if (seg == 0) atomicAdd(&eh[(size_t)(T + s) * 128 + row], a);
        }
        __syncthreads();
      }
    } else if (bid < 174) {  // ---- Dt ----
      if (ph < 127) {
        const int g = bid - 166;
        {
          float2 v = cld2(dbnd + (size_t)ph * 512 + 2 * tid);
          smV[2 * tid] = v.x;
          smV[2 * tid + 1] = v.y;
        }
        for (int i2 = tid; i2 < 512; i2 += TPB) {
          float2 v = cld2(uh0 + (size_t)(64 + T - 33) * 128 + 2 * i2);
          smW[2 * i2] = v.x;
          smW[2 * i2 + 1] = v.y;
        }
        __syncthreads();
        const int row = g * 64 + (tid >> 2);
        const int l4 = tid & 3;
        float a = 0.f;
        {
          const float4* m4 = (const float4*)(A8k + (size_t)row * 512 + l4 * 128);
          const float4* v4 = (const float4*)(smV + l4 * 128);
#pragma unroll
          for (int it = 0; it < 32; ++it) {
            float4 mm = m4[it], vv = v4[it];
            a += mm.x * vv.x + mm.y * vv.y + mm.z * vv.z + mm.w * vv.w;
          }
        }
#pragma unroll
        for (int m = 0; m < 8; ++m) {
          const float4* m4 = (const float4*)(AB33p + (size_t)m * 65536 + (size_t)row * 128 + l4 * 32);
          const float4* v4 = (const float4*)(smW + (7 - m) * 128 + l4 * 32);
#pragma unroll
          for (int it = 0; it < 8; ++it) {
            float4 mm = m4[it], vv = v4[it];
            a += mm.x * vv.x + mm.y * vv.y + mm.z * vv.z + mm.w * vv.w;
          }
        }
        a += __shfl_down(a, 2);
        a += __shfl_down(a, 1);
        if (l4 == 0) cst(&dbnd[(size_t)(ph + 1) * 512 + row], a);
        __syncthreads();
      }
    } else if (bid < 190) {  // ---- Xp ----
      if (ph >= 2 && ph < 130) {
        const int Tq = T - 16;
        const int r = bid - 174;
        const int s = r >> 1;
        const int half = (r & 1) << 8;
        {
          const float* src = (ph == 2) ? x0 : (xh + (size_t)(Tq - 1) * 512);
          float2 v = cld2(src + 2 * tid);
          smV[2 * tid] = v.x;
          smV[2 * tid + 1] = v.y;
        }
        __syncthreads();
        const int pslot = (ph == 2) ? s : (s + 1);
        const int row = half + tid;
        if (pslot == 0) {
          atomicAdd(&xh[(size_t)Tq * 512 + row], smV[row]);
        } else {
          const float4* m4 = (const float4*)(Pp + (size_t)(pslot - 1) * 262144 + (size_t)row * 512);
          const float4* v4 = (const float4*)smV;
          float a = 0.f;
#pragma unroll 8
          for (int it = 0; it < 128; ++it) {
            float4 mm = m4[it], vv = v4[it];
            a += mm.x * vv.x + mm.y * vv.y + mm.z * vv.z + mm.w * vv.w;
          }
          atomicAdd(&xh[(size_t)(Tq + s) * 512 + row], a);
        }
        __syncthreads();
      }
    } else if (bid < 206) {  // ---- Xr ----
      if (ph >= 2 && ph < 130) {
        const int Tq = T - 16;
        const int r = bid - 190;
        const int i = r >> 1;
        const int half = (r & 1) << 8;
        for (int i2 = tid; i2 < 512; i2 += TPB) {
          int idx = 2 * i2;
          float2 v;
          if (ph == 2 && idx < 128) {
            v.x = 0.f;
            v.y = 0.f;
          } else {
            v = cld2(eh + (size_t)(Tq - 1) * 128 + idx);
          }
          smW[idx] = v.x;
          smW[idx + 1] = v.y;
        }
        __syncthreads();
        const int row = half + tid;
        const float* Rrow = (i == 0) ? (B + (size_t)row * 128)
                                     : (Rnp + (size_t)(i - 1) * 65536 + (size_t)row * 128);
        const float4* m4 = (const float4*)Rrow;
        for (int s = i; s < 8; ++s) {
          const float4* e4 = (const float4*)(smW + (s - i) * 128);
          float a = 0.f;
#pragma unroll
          for (int it = 0; it < 32; ++it) {
            float4 mm = m4[it], vv = e4[it];
            a += mm.x * vv.x + mm.y * vv.y + mm.z * vv.z + mm.w * vv.w;
          }
          atomicAdd(&xh[(size_t)(Tq + s) * 512 + row], a);
        }
        __syncthreads();
      }
    } else {  // ---- U (bid 206..213) ----
      if (ph >= 3 && ph < 131) {
        const int Tu = T - 24;
        const int g = bid - 206;
        for (int i2 = tid; i2 < 2048; i2 += TPB) {
          int idx = 2 * i2;
          int rr = idx >> 9;
          int cc = idx & 511;
          float2 v = cld2(xh + (size_t)(Tu + rr) * 512 + cc);
          smVx[rr * 516 + cc] = v.x;
          smVx[rr * 516 + cc + 1] = v.y;
        }
        __syncthreads();
        const int o = tid >> 1;
        const int par = tid & 1;
        const int s = o >> 4;
        const int lr = o & 15;
        const int row = g * 16 + lr;
        const float4* m4 = (const float4*)(KC + (size_t)row * 512 + par * 256);
        const float4* v4 = (const float4*)(smVx + s * 516 + par * 256);
        float a = 0.f;
#pragma unroll
        for (int it = 0; it < 64; ++it) {
          float4 mm = m4[it], vv = v4[it];
          a += mm.x * vv.x + mm.y * vv.y + mm.z * vv.z + mm.w * vv.w;
        }
        a += __shfl_down(a, 1);
        if (par == 0) {
          float u = cld(&eh[(size_t)(Tu + s) * 128 + row]) - a;
          cst(&uh0[(size_t)(64 + Tu + s) * 128 + row], u);
        }
        __syncthreads();
      }
    }

    grid_barrier(arr, bid, tid, (unsigned)(ph + 1));
  }
}

// ---------------------------------------------------------------------------
// Epilogue: y_obs_t = C x_t; cost_t = y'Q y + u'R u.  (one WG per t)
// ---------------------------------------------------------------------------
__global__ __launch_bounds__(256) void cost_kernel(const float* __restrict__ C,
    const float* __restrict__ Q, const float* __restrict__ R,
    const float* __restrict__ xh, const float* __restrict__ uh0,
    float* __restrict__ out) {
  __shared__ float xs[512];
  __shared__ float ys[256];
  __shared__ float us[128];
  __shared__ float redw[4];
  const int t = blockIdx.x;
  const int tid = threadIdx.x;
  {
    float2 v = cld2(xh + (size_t)t * 512 + 2 * tid);
    xs[2 * tid] = v.x;
    xs[2 * tid + 1] = v.y;
  }
  if (tid < 64) {
    float2 v = cld2(uh0 + (size_t)(64 + t) * 128 + 2 * tid);
    us[2 * tid] = v.x;
    us[2 * tid + 1] = v.y;
  }
  __syncthreads();
  {
    const float4* m4 = (const float4*)(C + (size_t)tid * 512);
    const float4* v4 = (const float4*)xs;
    float a = 0.f;
    for (int it = 0; it < 128; ++it) {
      float4 mm = m4[it], vv = v4[it];
      a += mm.x * vv.x + mm.y * vv.y + mm.z * vv.z + mm.w * vv.w;
    }
    ys[tid] = a;
  }
  __syncthreads();
  float acc;
  {
    const float* Qr = Q + (size_t)tid * 256;
    float qy = 0.f;
    for (int k = 0; k < 256; ++k) qy = fmaf(Qr[k], ys[k], qy);
    acc = qy * ys[tid];
  }
  if (tid < 128) {
    const float* Rr = R + (size_t)tid * 128;
    float ru = 0.f;
    for (int k = 0; k < 128; ++k) ru = fmaf(Rr[k], us[k], ru);
    acc += ru * us[tid];
  }
  float v = acc;
  v += __shfl_xor(v, 32);
  v += __shfl_xor(v, 16);
  v += __shfl_xor(v, 8);
  v += __shfl_xor(v, 4);
  v += __shfl_xor(v, 2);
  v += __shfl_xor(v, 1);
  if ((tid & 63) == 0) redw[tid >> 6] = v;
  __syncthreads();
  if (tid == 0) out[t] = redw[0] + redw[1] + redw[2] + redw[3];
}

// ---------------------------------------------------------------------------
extern "C" void kernel_launch(void* const* d_in, const int* in_sizes, int n_in,
                              void* d_out, int out_size, void* d_ws, size_t ws_size,
                              hipStream_t stream) {
  (void)in_sizes; (void)n_in; (void)out_size; (void)ws_size;
  const float* A = (const float*)d_in[0];
  const float* B = (const float*)d_in[1];
  const float* C = (const float*)d_in[2];
  const float* Q = (const float*)d_in[3];
  const float* R = (const float*)d_in[4];
  const float* Km = (const float*)d_in[5];
  const float* MT = (const float*)d_in[6];
  const float* Phi = (const float*)d_in[7];
  const float* sm = (const float*)d_in[8];
  const float* x0 = (const float*)d_in[9];

  float* ws = (float*)d_ws;
  // ---- ws layout (float offsets) ----
  const int oWfir = 0;               // 2,097,152
  const int oKC = 2097152;           // 65,536
  const int oW0C = 2162688;          // 65,536
  const int oAcl = 2228224;          // 262,144
  const int oP = 2490368;            // 8 x 262144  (P[1..8])
  const int oCA = 4587520;           // 7 x 131072  (CA[1..7])
  const int oW0CA = 5505024;         // 7 x 65536   (W0CA[1..7])
  const int oRn = 5963776;           // 7 x 65536   (Rn[1..7])
  const int oApB = 6422528;          // 8 x 65536   (ApB[1..8])
  const int oAB33 = 6946816;         // 8 x 65536   (AB33[0..7])
  const int oCAB33 = 7471104;        // 7 x 32768
  const int oW0CAB33 = 7700480;      // 7 x 16384
  const int oA2 = 7815168;           // 262,144
  const int oA4 = 8077312;
  const int oA8 = 8339456;
  const int oA16 = 8601600;
  const int oA32 = 8863744;
  const int oM2 = 9125888;           // 1,048,576 (BKC aliases after wfir)
  const int oBKC = oM2;
  const int oxh = 10174464;          // 524,288
  const int ouh0 = 10698752;         // 139,264  ((64+1024)x128)
  const int oeh = 10838016;          // 139,264  (1088x128)
  const int oynh = 10977280;         // 262,144
  const int odbnd = 11239424;        // 131x512 = 67,072
  const int oarr = 11306496;         // NWG*32 u32

  float* xh = ws + oxh;
  float* uh0 = ws + ouh0;
  float* eh = ws + oeh;
  float* ynh = ws + oynh;
  float* dbnd = ws + odbnd;
  unsigned* arr = (unsigned*)(ws + oarr);

  JobBatch jb;
  jb.n = 0;
  jb.start[0] = 0;
  auto J = [&](int xs_, int xo, int ys_, int yo, int zo, int M, int N, int K) {
    int i = jb.n++;
    jb.xsel[i] = xs_; jb.xoff[i] = xo; jb.ysel[i] = ys_; jb.yoff[i] = yo;
    jb.zoff[i] = zo; jb.M[i] = M; jb.N[i] = N; jb.K[i] = K;
    jb.start[i + 1] = jb.start[i] + (M >> 6) * (N >> 6);
  };
  auto L = [&]() {
    multi_gemm<<<dim3(jb.start[jb.n]), dim3(256), 0, stream>>>(jb, A, B, C, Km, ws);
    jb.n = 0;
    jb.start[0] = 0;
  };

  init_kernel<<<dim3(2048), dim3(256), 0, stream>>>(x0, xh, eh, ynh, uh0, dbnd, arr);
  m2_kernel<<<dim3(4096), dim3(256), 0, stream>>>(MT, sm, ws + oM2);
  wfir_kernel<<<dim3(8192), dim3(256), 0, stream>>>(ws + oM2, Phi, ws + oWfir);

  // ---- L1 ----
  J(4, 0, 3, 0, oKC, 128, 512, 256);          // KC = Km@C
  J(1, 0, 1, 0, oA2, 512, 512, 512);          // A2
  J(1, 0, 2, 0, oApB, 512, 128, 512);         // ApB1 = A@B
  J(3, 0, 1, 0, oCA, 256, 512, 512);          // CA1 = C@A
  L();
  // ---- L2 ----
  J(2, 0, 0, oKC, oBKC, 512, 512, 128);       // BKC
  J(0, oA2, 0, oA2, oA4, 512, 512, 512);      // A4
  J(0, oCA, 1, 0, oCA + 131072, 256, 512, 512);      // CA2
  J(1, 0, 0, oApB, oApB + 65536, 512, 128, 512);     // ApB2
  J(0, oWfir, 3, 0, oW0C, 128, 512, 256);     // W0C = W[0]@C
  L();
  axpy_acl<<<dim3(1024), dim3(256), 0, stream>>>(A, ws + oBKC, ws + oAcl, ws + oP);
  // ---- L3 ----
  J(0, oA4, 0, oA4, oA8, 512, 512, 512);                          // A8
  J(0, oP, 0, oP, oP + 262144, 512, 512, 512);                    // P2
  J(0, oCA, 0, oA2, oCA + 2 * 131072, 256, 512, 512);             // CA3
  J(0, oCA + 131072, 0, oA2, oCA + 3 * 131072, 256, 512, 512);    // CA4
  J(0, oW0C, 1, 0, oW0CA, 128, 512, 512);                         // W0CA1
  J(0, oW0C, 0, oA2, oW0CA + 65536, 128, 512, 512);               // W0CA2
  J(0, oA2, 0, oApB, oApB + 2 * 65536, 512, 128, 512);            // ApB3
  J(0, oA2, 0, oApB + 65536, oApB + 3 * 65536, 512, 128, 512);    // ApB4
  L();
  // ---- L4 ----
  J(0, oA8, 0, oA8, oA16, 512, 512, 512);                         // A16
  J(0, oP, 0, oP + 262144, oP + 2 * 262144, 512, 512, 512);       // P3
  J(0, oP + 262144, 0, oP + 262144, oP + 3 * 262144, 512, 512, 512);  // P4
  for (int i = 1; i <= 3; ++i)                                    // CA5..CA7
    J(0, oCA + (i - 1) * 131072, 0, oA4, oCA + (i + 3) * 131072, 256, 512, 512);
  for (int i = 1; i <= 2; ++i)                                    // W0CA3,4
    J(0, oW0CA + (i - 1) * 65536, 0, oA2, oW0CA + (i + 1) * 65536, 128, 512, 512);
  for (int k = 1; k <= 4; ++k)                                    // ApB5..8
    J(0, oA4, 0, oApB + (k - 1) * 65536, oApB + (k + 3) * 65536, 512, 128, 512);
  J(0, oP, 2, 0, oRn, 512, 128, 512);                             // Rn1
  J(0, oP + 262144, 2, 0, oRn + 65536, 512, 128, 512);            // Rn2
  L();
  // ---- L5 ----
  J(0, oA16, 0, oA16, oA32, 512, 512, 512);                       // A32
  for (int i = 1; i <= 4; ++i)                                    // P5..P8 = P[i]@P4
    J(0, oP + (i - 1) * 262144, 0, oP + 3 * 262144, oP + (i + 3) * 262144, 512, 512, 512);
  for (int i = 1; i <= 3; ++i)                                    // W0CA5..7
    J(0, oW0CA + (i - 1) * 65536, 0, oA4, oW0CA + (i + 3) * 65536, 128, 512, 512);
  J(0, oP + 2 * 262144, 2, 0, oRn + 2 * 65536, 512, 128, 512);    // Rn3
  J(0, oP + 3 * 262144, 2, 0, oRn + 3 * 65536, 512, 128, 512);    // Rn4
  L();
  // ---- L6 ----
  for (int m = 0; m <= 7; ++m)                                    // AB33[0..7]
    J(0, oA32, 0, oApB + m * 65536, oAB33 + m * 65536, 512, 128, 512);
  for (int i = 5; i <= 7; ++i)                                    // Rn5..7
    J(0, oP + (i - 1) * 262144, 2, 0, oRn + (i - 1) * 65536, 512, 128, 512);
  L();
  // ---- L7 ----
  for (int m = 0; m <= 6; ++m)                                    // CAB33[0..6]
    J(3, 0, 0, oAB33 + m * 65536, oCAB33 + m * 32768, 256, 128, 512);
  for (int m = 0; m <= 6; ++m)                                    // W0CAB33[0..6]
    J(0, oW0C, 0, oAB33 + m * 65536, oW0CAB33 + m * 16384, 128, 128, 512);
  L();

  main_kernel<<<dim3(NWG), dim3(TPB), 0, stream>>>(
      B, C, x0, ws + oWfir, ws + oKC, ws + oW0C, ws + oP, ws + oCA,
      ws + oW0CA, ws + oRn, ws + oAB33, ws + oCAB33, ws + oW0CAB33,
      ws + oA8, xh, uh0, eh, ynh, dbnd, arr);

  cost_kernel<<<dim3(1024), dim3(256), 0, stream>>>(C, Q, R, xh, uh0,
                                                    (float*)d_out);
}